// Round 7
// baseline (6228.528 us; speedup 1.0000x reference)
//
#include <hip/hip_runtime.h>
#include <math.h>

#define DEV __device__ __forceinline__

constexpr int NNODE = 8192;

DEV float wsum64(float x){
#pragma unroll
  for(int m=32;m>=1;m>>=1) x += __shfl_xor(x,m,64);
  return x;
}
DEV float siluf(float x){ return x/(1.0f+__expf(-x)); }
DEV float sigmf(float x){ return 1.0f/(1.0f+__expf(-x)); }
DEV float lreluf(float x){ return x>0.0f ? x : 0.2f*x; }
DEV float pick4(float a0,float a1,float a2,float a3,int h){
  float x=(h&1)?a1:a0;
  float y=(h&1)?a3:a2;
  return (h&2)?y:x;
}

// ---------------- CSR build ----------------
__global__ void k_csr(const int* __restrict__ esrc, int E, int N, int* __restrict__ row_start){
  int n = blockIdx.x*blockDim.x + threadIdx.x;
  if(n > N) return;
  int lo=0, hi=E;
  while(lo<hi){ int mid=(lo+hi)>>1; if(esrc[mid] < n) lo=mid+1; else hi=mid; }
  row_start[n]=lo;
}

// ---------------- per directed edge: dist + spherical harmonics ----------------
__global__ void k_geom(const float* __restrict__ pos, const int* __restrict__ esrc,
                       const int* __restrict__ edst, int E,
                       float* __restrict__ dist, float* __restrict__ sh){
  int e = blockIdx.x*blockDim.x + threadIdx.x;
  if(e>=E) return;
  int a=esrc[e], b=edst[e];
  float x=pos[3*a+0]-pos[3*b+0];
  float y=pos[3*a+1]-pos[3*b+1];
  float z=pos[3*a+2]-pos[3*b+2];
  float d=sqrtf(x*x+y*y+z*z);
  dist[e]=d;
  float id=1.0f/(d+1e-9f);
  float ux=x*id, uy=y*id, uz=z*id;
  const float s3=1.7320508075688772f, c15=3.872983346207417f, c5=2.23606797749979f;
  float* o = sh + (size_t)e*8;
  o[0]=s3*uy; o[1]=s3*uz; o[2]=s3*ux;
  o[3]=c15*ux*uy; o[4]=c15*uy*uz; o[5]=0.5f*c5*(3.0f*uz*uz-1.0f);
  o[6]=c15*ux*uz; o[7]=0.5f*c15*(ux*ux-uy*uy);
}

// ---------------- canonical pair ranking ----------------
__global__ void k_rank1(const int* __restrict__ esrc, const int* __restrict__ edst,
                        const float* __restrict__ dist, int E, int Ec,
                        int* __restrict__ cnt, int* __restrict__ prank, float* __restrict__ cdist){
  int e = blockIdx.x*blockDim.x + threadIdx.x;
  if(e>=E) return;
  int sn=esrc[e], dn=edst[e];
  if(sn<dn){
    int r=atomicAdd(cnt,1);
    if(r<Ec){ prank[e]=r; cdist[r]=dist[e]; } else prank[e]=0;
  }
}
__global__ void k_rank2(const int* __restrict__ esrc, const int* __restrict__ edst,
                        const int* __restrict__ row_start, int E, int* __restrict__ prank){
  int e = blockIdx.x*blockDim.x + threadIdx.x;
  if(e>=E) return;
  int sn=esrc[e], dn=edst[e];
  if(sn>dn){
    int lo=row_start[dn], hi=row_start[dn+1];
    while(lo<hi){ int mid=(lo+hi)>>1; if(edst[mid]<sn) lo=mid+1; else hi=mid; }
    prank[e]=prank[lo];
  }
}

// ---------------- rbf precompute ----------------
__global__ void k_rbf(const float* __restrict__ cdist, int Ec, float* __restrict__ rbf){
  int idx = blockIdx.x*blockDim.x + threadIdx.x;
  if(idx >= Ec*128) return;
  int e=idx>>7, k=idx&127;
  float d=cdist[e];
  float ck=(30.0f/127.0f)*(float)k;
  float dt=d-ck;
  const float gamma = 0.5f/((30.0f/128.0f)*(30.0f/128.0f));
  rbf[idx]=__expf(-gamma*dt*dt);
}

// ---------------- radial MLP per layer (32 edges/block) ----------------
__global__ __launch_bounds__(256) void k_wr2(const float* __restrict__ rbf, int Ec,
    const float* __restrict__ W1, const float* __restrict__ W2, float* __restrict__ wr){
  __shared__ float RB[32][132];
  __shared__ float H[32][72];
  int tid=threadIdx.x;
  int base=blockIdx.x*32;
#pragma unroll
  for(int i=0;i<16;i++){
    int idx=tid+256*i;
    int r=idx>>7, c=idx&127;
    RB[r][c]=(base+r<Ec)? rbf[(size_t)(base+r)*128+c] : 0.0f;
  }
  __syncthreads();
  int j=tid&63, g=tid>>6;
  int eg=g*8;
  float acc[8];
#pragma unroll
  for(int e=0;e<8;e++) acc[e]=0.0f;
  for(int k=0;k<128;k+=4){
    float w0=W1[k*64+j], w1=W1[(k+1)*64+j], w2=W1[(k+2)*64+j], w3=W1[(k+3)*64+j];
#pragma unroll
    for(int e=0;e<8;e++){
      const float4 rv=*reinterpret_cast<const float4*>(&RB[eg+e][k]);
      acc[e]=fmaf(rv.x,w0,acc[e]); acc[e]=fmaf(rv.y,w1,acc[e]);
      acc[e]=fmaf(rv.z,w2,acc[e]); acc[e]=fmaf(rv.w,w3,acc[e]);
    }
  }
#pragma unroll
  for(int e=0;e<8;e++) H[eg+e][j]=siluf(acc[e]);
  __syncthreads();
  for(int c0=0;c0<320;c0+=64){
    float a2[8];
#pragma unroll
    for(int e=0;e<8;e++) a2[e]=0.0f;
    for(int k=0;k<64;k+=4){
      float w0=W2[k*320+c0+j], w1=W2[(k+1)*320+c0+j], w2=W2[(k+2)*320+c0+j], w3=W2[(k+3)*320+c0+j];
#pragma unroll
      for(int e=0;e<8;e++){
        const float4 hv=*reinterpret_cast<const float4*>(&H[eg+e][k]);
        a2[e]=fmaf(hv.x,w0,a2[e]); a2[e]=fmaf(hv.y,w1,a2[e]);
        a2[e]=fmaf(hv.z,w2,a2[e]); a2[e]=fmaf(hv.w,w3,a2[e]);
      }
    }
#pragma unroll
    for(int e=0;e<8;e++){
      if(base+eg+e<Ec) wr[(size_t)(base+eg+e)*320+c0+j]=a2[e];
    }
  }
}

// ---------------- init edge MLP ----------------
__global__ __launch_bounds__(256) void k_dw3(const float* __restrict__ rbf, int Ec,
    const float* __restrict__ W1, const float* __restrict__ W2, const float* __restrict__ W3,
    float* __restrict__ dw){
  __shared__ float RB[64][132];
  __shared__ float H1[64][72];
  __shared__ float H2[64][72];
  int tid=threadIdx.x;
  int base=blockIdx.x*64;
#pragma unroll
  for(int i=0;i<32;i++){
    int idx=tid+256*i;
    int r=idx>>7, c=idx&127;
    RB[r][c]=(base+r<Ec)? rbf[(size_t)(base+r)*128+c] : 0.0f;
  }
  __syncthreads();
  int j=tid&63, g=tid>>6;
  int e0=g*16;
  float acc[16];
#pragma unroll
  for(int e=0;e<16;e++) acc[e]=0.0f;
  for(int k=0;k<128;k+=4){
    float w0=W1[k*64+j], w1=W1[(k+1)*64+j], w2=W1[(k+2)*64+j], w3=W1[(k+3)*64+j];
#pragma unroll
    for(int e=0;e<16;e++){
      const float4 rv=*reinterpret_cast<const float4*>(&RB[e0+e][k]);
      acc[e]=fmaf(rv.x,w0,acc[e]); acc[e]=fmaf(rv.y,w1,acc[e]);
      acc[e]=fmaf(rv.z,w2,acc[e]); acc[e]=fmaf(rv.w,w3,acc[e]);
    }
  }
#pragma unroll
  for(int e=0;e<16;e++) H1[e0+e][j]=siluf(acc[e]);
  __syncthreads();
#pragma unroll
  for(int e=0;e<16;e++) acc[e]=0.0f;
  for(int k=0;k<64;k+=4){
    float w0=W2[k*64+j], w1=W2[(k+1)*64+j], w2=W2[(k+2)*64+j], w3=W2[(k+3)*64+j];
#pragma unroll
    for(int e=0;e<16;e++){
      const float4 hv=*reinterpret_cast<const float4*>(&H1[e0+e][k]);
      acc[e]=fmaf(hv.x,w0,acc[e]); acc[e]=fmaf(hv.y,w1,acc[e]);
      acc[e]=fmaf(hv.z,w2,acc[e]); acc[e]=fmaf(hv.w,w3,acc[e]);
    }
  }
#pragma unroll
  for(int e=0;e<16;e++) H2[e0+e][j]=siluf(acc[e]);
  __syncthreads();
  for(int c0=0;c0<224;c0+=64){
    int c=c0+j;
    bool ok = c<224;
    int cc = ok? c : 0;
    float a2[16];
#pragma unroll
    for(int e=0;e<16;e++) a2[e]=0.0f;
    for(int k=0;k<64;k+=4){
      float w0=W3[k*224+cc], w1=W3[(k+1)*224+cc], w2=W3[(k+2)*224+cc], w3=W3[(k+3)*224+cc];
#pragma unroll
      for(int e=0;e<16;e++){
        const float4 hv=*reinterpret_cast<const float4*>(&H2[e0+e][k]);
        a2[e]=fmaf(hv.x,w0,a2[e]); a2[e]=fmaf(hv.y,w1,a2[e]);
        a2[e]=fmaf(hv.z,w2,a2[e]); a2[e]=fmaf(hv.w,w3,a2[e]);
      }
    }
#pragma unroll
    for(int e=0;e<16;e++){
      if(ok && base+e0+e<Ec) dw[(size_t)(base+e0+e)*224+c]=a2[e];
    }
  }
}

// ---------------- node init ----------------
__global__ __launch_bounds__(64) void k_nodeinit(const float* __restrict__ tt, const int* __restrict__ fin,
    const float* __restrict__ Wemb, const int* __restrict__ row_start, const int* __restrict__ prank,
    const float* __restrict__ sh, const float* __restrict__ dw,
    float* __restrict__ S, float* __restrict__ V, float* __restrict__ Q){
  int n=blockIdx.x, lane=threadIdx.x;
  __shared__ float te[64];
  float tn=tt[n];
  if(lane<32){
    float fr=__expf(-9.210340371976184f*((float)lane/32.0f));
    float ang=tn*10000.0f*fr;
    te[lane]=sinf(ang);
    te[32+lane]=cosf(ang);
  }
  __syncthreads();
  int f=fin[n];
  float s0=Wemb[f*128+lane], s1=Wemb[f*128+64+lane];
  for(int j=0;j<64;j++){
    float tb=te[j];
    s0=fmaf(tb,Wemb[(20+j)*128+lane],s0);
    s1=fmaf(tb,Wemb[(20+j)*128+64+lane],s1);
  }
  float aS0=0,aS1=0,aV0=0,aV1=0,aV2=0,aQ0=0,aQ1=0,aQ2=0,aQ3=0,aQ4=0;
  int e0=row_start[n], e1=row_start[n+1];
  for(int e=e0;e<e1;e++){
    const float* de = dw + (size_t)prank[e]*224;
    const float* se = sh + (size_t)e*8;
    aS0+=de[lane]; aS1+=de[64+lane];
    float w1=de[128+lane];
    aV0=fmaf(w1,-se[0],aV0); aV1=fmaf(w1,-se[1],aV1); aV2=fmaf(w1,-se[2],aV2);
    if(lane<32){
      float w2=de[192+lane];
      aQ0=fmaf(w2,se[3],aQ0); aQ1=fmaf(w2,se[4],aQ1); aQ2=fmaf(w2,se[5],aQ2);
      aQ3=fmaf(w2,se[6],aQ3); aQ4=fmaf(w2,se[7],aQ4);
    }
  }
  const float inv = 1.0f/sqrtf(15.57930850982666f);
  S[(size_t)n*128+lane]=s0+inv*aS0;
  S[(size_t)n*128+64+lane]=s1+inv*aS1;
  V[(size_t)n*192+lane*3+0]=inv*aV0;
  V[(size_t)n*192+lane*3+1]=inv*aV1;
  V[(size_t)n*192+lane*3+2]=inv*aV2;
  if(lane<32){
    Q[(size_t)n*160+lane*5+0]=inv*aQ0;
    Q[(size_t)n*160+lane*5+1]=inv*aQ1;
    Q[(size_t)n*160+lane*5+2]=inv*aQ2;
    Q[(size_t)n*160+lane*5+3]=inv*aQ3;
    Q[(size_t)n*160+lane*5+4]=inv*aQ4;
  }
}

// ---------------- eq_ln(g1) + per-node projections (4 waves x 2 nodes) ----------
__global__ __launch_bounds__(256) void k_nodemm(
    const float* __restrict__ S, const float* __restrict__ V, const float* __restrict__ Q,
    const float* __restrict__ g1s, const float* __restrict__ g1v, const float* __restrict__ g1q,
    const float* __restrict__ Ws, const float* __restrict__ Wsd, const float* __restrict__ Wsv,
    const float* __restrict__ Wsq, const float* __restrict__ Wv, const float* __restrict__ Wq,
    float* __restrict__ Pa, float* __restrict__ Pb, float* __restrict__ Pc, float* __restrict__ Pd,
    float* __restrict__ PVb, float* __restrict__ PQb){
  int tid=threadIdx.x; int lane=tid&63; int wv=tid>>6;
  int nb=blockIdx.x*8+wv*2;
  __shared__ float Yall[4][2*480];
  float* Y=Yall[wv];
  for(int t=0;t<2;t++){
    int n=nb+t;
    float s0=S[(size_t)n*128+lane], s1=S[(size_t)n*128+64+lane];
    float mu=wsum64(s0+s1)*(1.0f/128.0f);
    float c0=s0-mu, c1=s1-mu;
    float var=wsum64(c0*c0+c1*c1)*(1.0f/128.0f);
    float rs=rsqrtf(var+1e-5f);
    Y[t*480+lane]=c0*rs*g1s[lane];
    Y[t*480+64+lane]=c1*rs*g1s[64+lane];
    float vx=V[(size_t)n*192+lane*3+0], vy=V[(size_t)n*192+lane*3+1], vz=V[(size_t)n*192+lane*3+2];
    float nv=wsum64(vx*vx+vy*vy+vz*vz)*(1.0f/64.0f);
    float rv=rsqrtf(nv+1e-5f)*g1v[lane];
    Y[t*480+128+lane*3+0]=vx*rv;
    Y[t*480+128+lane*3+1]=vy*rv;
    Y[t*480+128+lane*3+2]=vz*rv;
    float q0=0,q1=0,q2=0,q3=0,q4=0,qs=0;
    if(lane<32){
      q0=Q[(size_t)n*160+lane*5+0]; q1=Q[(size_t)n*160+lane*5+1]; q2=Q[(size_t)n*160+lane*5+2];
      q3=Q[(size_t)n*160+lane*5+3]; q4=Q[(size_t)n*160+lane*5+4];
      qs=q0*q0+q1*q1+q2*q2+q3*q3+q4*q4;
    }
    float nq=wsum64(qs)*(1.0f/32.0f);
    float rq=rsqrtf(nq+1e-5f);
    if(lane<32){
      float g=g1q[lane]*rq;
      Y[t*480+320+lane*5+0]=q0*g; Y[t*480+320+lane*5+1]=q1*g; Y[t*480+320+lane*5+2]=q2*g;
      Y[t*480+320+lane*5+3]=q3*g; Y[t*480+320+lane*5+4]=q4*g;
    }
  }
  __syncthreads();
  float pa0[2],pa1[2],pb0[2],pb1[2];
#pragma unroll
  for(int t=0;t<2;t++){pa0[t]=0;pa1[t]=0;pb0[t]=0;pb1[t]=0;}
  for(int k=0;k<128;k++){
    float wa0=Ws[k*128+lane], wa1=Ws[k*128+64+lane];
    float wb0=Wsd[k*128+lane], wb1=Wsd[k*128+64+lane];
#pragma unroll
    for(int t=0;t<2;t++){
      float y=Y[t*480+k];
      pa0[t]=fmaf(y,wa0,pa0[t]); pa1[t]=fmaf(y,wa1,pa1[t]);
      pb0[t]=fmaf(y,wb0,pb0[t]); pb1[t]=fmaf(y,wb1,pb1[t]);
    }
  }
#pragma unroll
  for(int t=0;t<2;t++){
    size_t n=nb+t;
    Pa[n*128+lane]=pa0[t]; Pa[n*128+64+lane]=pa1[t];
    Pb[n*128+lane]=pb0[t]; Pb[n*128+64+lane]=pb1[t];
  }
  float pc[2],pd[2];
#pragma unroll
  for(int t=0;t<2;t++){pc[t]=0;pd[t]=0;}
  for(int k=0;k<128;k++){
    float wc=Wsv[k*64+lane];
    float wd=(lane<32)?Wsq[k*32+lane]:0.0f;
#pragma unroll
    for(int t=0;t<2;t++){
      float y=Y[t*480+k];
      pc[t]=fmaf(y,wc,pc[t]); pd[t]=fmaf(y,wd,pd[t]);
    }
  }
#pragma unroll
  for(int t=0;t<2;t++){
    size_t n=nb+t;
    Pc[n*64+lane]=pc[t];
    if(lane<32) Pd[n*32+lane]=pd[t];
  }
  float pV[2][3];
#pragma unroll
  for(int t=0;t<2;t++){pV[t][0]=0;pV[t][1]=0;pV[t][2]=0;}
  for(int j=0;j<64;j++){
    float w=Wv[j*64+lane];
#pragma unroll
    for(int t=0;t<2;t++){
#pragma unroll
      for(int c=0;c<3;c++) pV[t][c]=fmaf(Y[t*480+128+j*3+c],w,pV[t][c]);
    }
  }
#pragma unroll
  for(int t=0;t<2;t++){
    size_t n=nb+t;
#pragma unroll
    for(int c=0;c<3;c++) PVb[n*192+lane*3+c]=pV[t][c];
  }
  float pQ[2][5];
#pragma unroll
  for(int t=0;t<2;t++){
#pragma unroll
    for(int c=0;c<5;c++) pQ[t][c]=0;
  }
  for(int j=0;j<32;j++){
    float w=(lane<32)?Wq[j*32+lane]:0.0f;
#pragma unroll
    for(int t=0;t<2;t++){
#pragma unroll
      for(int c=0;c<5;c++) pQ[t][c]=fmaf(Y[t*480+320+j*5+c],w,pQ[t][c]);
    }
  }
  if(lane<32){
#pragma unroll
    for(int t=0;t<2;t++){
      size_t n=nb+t;
#pragma unroll
      for(int c=0;c<5;c++) PQb[n*160+lane*5+c]=pQ[t][c];
    }
  }
}

// ---------------- attention: 2-chain unrolled online segment-softmax ------------
__global__ __launch_bounds__(64) void k_attn(
    const int* __restrict__ row_start, const int* __restrict__ edst, const int* __restrict__ prank,
    const float* __restrict__ sh, const float* __restrict__ wr,
    const float* __restrict__ Pa, const float* __restrict__ Pb, const float* __restrict__ Pc,
    const float* __restrict__ Pd, const float* __restrict__ PVb, const float* __restrict__ PQb,
    const float* __restrict__ Amat,
    float* __restrict__ aS, float* __restrict__ aV, float* __restrict__ aQ){
  int n=blockIdx.x, lane=threadIdx.x;
  int e0=row_start[n], e1=row_start[n+1];
  float b0=Pb[(size_t)n*128+lane], b1=Pb[(size_t)n*128+64+lane];
  int d5=lane>>5;
  float A0=Amat[d5*32+(lane&31)];
  float A1=Amat[(2+d5)*32+(lane&31)];
  int hv=lane>>4;
  int hq=(lane&31)>>3;
  float M0A=-1e30f,M1A=-1e30f,M2A=-1e30f,M3A=-1e30f,D0A=0,D1A=0,D2A=0,D3A=0;
  float s0aA=0,s1aA=0,v0aA=0,v1aA=0,v2aA=0,q0aA=0,q1aA=0,q2aA=0,q3aA=0,q4aA=0;
  float M0B=-1e30f,M1B=-1e30f,M2B=-1e30f,M3B=-1e30f,D0B=0,D1B=0,D2B=0,D3B=0;
  float s0aB=0,s1aB=0,v0aB=0,v1aB=0,v2aB=0,q0aB=0,q1aB=0,q2aB=0,q3aB=0,q4aB=0;

#define ATTN_EDGE(EE, M0,M1,M2,M3,D0,D1,D2,D3,s0a,s1a,v0a,v1a,v2a,q0a,q1a,q2a,q3a,q4a) do{ \
    int m_=edst[EE]; \
    const float* wre_ = wr + (size_t)prank[EE]*320; \
    const float* se_  = sh + (size_t)(EE)*8; \
    float ms0=(Pa[(size_t)m_*128+lane]+b0)*wre_[lane]; \
    float ms1=(Pa[(size_t)m_*128+64+lane]+b1)*wre_[64+lane]; \
    float l0=lreluf(ms0)*A0; \
    float l1=lreluf(ms1)*A1; \
    for(int mk_=16;mk_>=1;mk_>>=1){ l0+=__shfl_xor(l0,mk_,32); l1+=__shfl_xor(l1,mk_,32); } \
    float lg0=__shfl(l0,0,64), lg1=__shfl(l0,32,64); \
    float lg2=__shfl(l1,0,64), lg3=__shfl(l1,32,64); \
    float Mn_,f0_,f1_,f2_,f3_,ee0_,ee1_,ee2_,ee3_; \
    Mn_=fmaxf(M0,lg0); f0_=__expf(M0-Mn_); ee0_=__expf(lg0-Mn_); D0=D0*f0_+ee0_; M0=Mn_; \
    Mn_=fmaxf(M1,lg1); f1_=__expf(M1-Mn_); ee1_=__expf(lg1-Mn_); D1=D1*f1_+ee1_; M1=Mn_; \
    Mn_=fmaxf(M2,lg2); f2_=__expf(M2-Mn_); ee2_=__expf(lg2-Mn_); D2=D2*f2_+ee2_; M2=Mn_; \
    Mn_=fmaxf(M3,lg3); f3_=__expf(M3-Mn_); ee3_=__expf(lg3-Mn_); D3=D3*f3_+ee3_; M3=Mn_; \
    float fs0=d5?f1_:f0_, es0=d5?ee1_:ee0_; \
    float fs1=d5?f3_:f2_, es1=d5?ee3_:ee2_; \
    s0a=s0a*fs0+es0*ms0; \
    s1a=s1a*fs1+es1*ms1; \
    float fv=pick4(f0_,f1_,f2_,f3_,hv), ev=pick4(ee0_,ee1_,ee2_,ee3_,hv); \
    float aw1a=wre_[128+lane], aw1b=wre_[192+lane]; \
    float t1=Pc[(size_t)m_*64+lane]*aw1a; \
    float mv0=fmaf(PVb[(size_t)m_*192+lane*3+0],aw1b,-t1*se_[0]); \
    float mv1=fmaf(PVb[(size_t)m_*192+lane*3+1],aw1b,-t1*se_[1]); \
    float mv2=fmaf(PVb[(size_t)m_*192+lane*3+2],aw1b,-t1*se_[2]); \
    v0a=v0a*fv+ev*mv0; v1a=v1a*fv+ev*mv1; v2a=v2a*fv+ev*mv2; \
    if(lane<32){ \
      float fq=pick4(f0_,f1_,f2_,f3_,hq), eq=pick4(ee0_,ee1_,ee2_,ee3_,hq); \
      float aw2a=wre_[256+lane], aw2b=wre_[288+lane]; \
      float t2=Pd[(size_t)m_*32+lane]*aw2a; \
      float mq0=fmaf(PQb[(size_t)m_*160+lane*5+0],aw2b,t2*se_[3]); \
      float mq1=fmaf(PQb[(size_t)m_*160+lane*5+1],aw2b,t2*se_[4]); \
      float mq2=fmaf(PQb[(size_t)m_*160+lane*5+2],aw2b,t2*se_[5]); \
      float mq3=fmaf(PQb[(size_t)m_*160+lane*5+3],aw2b,t2*se_[6]); \
      float mq4=fmaf(PQb[(size_t)m_*160+lane*5+4],aw2b,t2*se_[7]); \
      q0a=q0a*fq+eq*mq0; q1a=q1a*fq+eq*mq1; q2a=q2a*fq+eq*mq2; \
      q3a=q3a*fq+eq*mq3; q4a=q4a*fq+eq*mq4; \
    } \
  }while(0)

  for(int e=e0;e<e1;e+=2){
    ATTN_EDGE(e, M0A,M1A,M2A,M3A,D0A,D1A,D2A,D3A,s0aA,s1aA,v0aA,v1aA,v2aA,q0aA,q1aA,q2aA,q3aA,q4aA);
    if(e+1<e1){
      ATTN_EDGE(e+1, M0B,M1B,M2B,M3B,D0B,D1B,D2B,D3B,s0aB,s1aB,v0aB,v1aB,v2aB,q0aB,q1aB,q2aB,q3aB,q4aB);
    }
  }
#undef ATTN_EDGE

  // merge chains A,B (exact softmax merge per logit group)
  float Mf0=fmaxf(M0A,M0B), fA0=__expf(M0A-Mf0), fB0=__expf(M0B-Mf0);
  float Mf1=fmaxf(M1A,M1B), fA1=__expf(M1A-Mf1), fB1=__expf(M1B-Mf1);
  float Mf2=fmaxf(M2A,M2B), fA2=__expf(M2A-Mf2), fB2=__expf(M2B-Mf2);
  float Mf3=fmaxf(M3A,M3B), fA3=__expf(M3A-Mf3), fB3=__expf(M3B-Mf3);
  float D0=D0A*fA0+D0B*fB0;
  float D1=D1A*fA1+D1B*fB1;
  float D2=D2A*fA2+D2B*fB2;
  float D3=D3A*fA3+D3B*fB3;
  float fsA0=d5?fA1:fA0, fsB0=d5?fB1:fB0;
  float fsA1=d5?fA3:fA2, fsB1=d5?fB3:fB2;
  float s0a=s0aA*fsA0+s0aB*fsB0;
  float s1a=s1aA*fsA1+s1aB*fsB1;
  float fvA=pick4(fA0,fA1,fA2,fA3,hv), fvB=pick4(fB0,fB1,fB2,fB3,hv);
  float v0a=v0aA*fvA+v0aB*fvB;
  float v1a=v1aA*fvA+v1aB*fvB;
  float v2a=v2aA*fvA+v2aB*fvB;
  float fqA=pick4(fA0,fA1,fA2,fA3,hq), fqB=pick4(fB0,fB1,fB2,fB3,hq);
  float q0a=q0aA*fqA+q0aB*fqB;
  float q1a=q1aA*fqA+q1aB*fqB;
  float q2a=q2aA*fqA+q2aB*fqB;
  float q3a=q3aA*fqA+q3aB*fqB;
  float q4a=q4aA*fqA+q4aB*fqB;

  float Ds0=d5?D1:D0, Ds1=d5?D3:D2;
  aS[(size_t)n*128+lane]=s0a/(Ds0+1e-9f);
  aS[(size_t)n*128+64+lane]=s1a/(Ds1+1e-9f);
  float Dv=pick4(D0,D1,D2,D3,hv);
  float iv=1.0f/(Dv+1e-9f);
  aV[(size_t)n*192+lane*3+0]=v0a*iv;
  aV[(size_t)n*192+lane*3+1]=v1a*iv;
  aV[(size_t)n*192+lane*3+2]=v2a*iv;
  if(lane<32){
    float Dq=pick4(D0,D1,D2,D3,hq);
    float iq=1.0f/(Dq+1e-9f);
    aQ[(size_t)n*160+lane*5+0]=q0a*iq;
    aQ[(size_t)n*160+lane*5+1]=q1a*iq;
    aQ[(size_t)n*160+lane*5+2]=q2a*iq;
    aQ[(size_t)n*160+lane*5+3]=q3a*iq;
    aQ[(size_t)n*160+lane*5+4]=q4a*iq;
  }
}

// ---------------- ffn_a: attn-out proj + residual + eq_ln(g2) (4w x 2n) ---------
__global__ __launch_bounds__(256) void k_ffn_a(
    float* __restrict__ S, float* __restrict__ V, float* __restrict__ Q,
    const float* __restrict__ aS, const float* __restrict__ aV, const float* __restrict__ aQ,
    const float* __restrict__ Wos, const float* __restrict__ Wov, const float* __restrict__ Woq,
    const float* __restrict__ g2s, const float* __restrict__ g2v, const float* __restrict__ g2q,
    float* __restrict__ Yb){
  int tid=threadIdx.x; int lane=tid&63; int wv=tid>>6;
  int nb=blockIdx.x*8+wv*2;
  __shared__ float AGall[4][2*480];
  float* AG=AGall[wv];
#pragma unroll
  for(int t=0;t<2;t++){
    size_t n=nb+t;
    AG[t*480+lane]=aS[n*128+lane];
    AG[t*480+64+lane]=aS[n*128+64+lane];
#pragma unroll
    for(int c=0;c<3;c++) AG[t*480+128+lane*3+c]=aV[n*192+lane*3+c];
    if(lane<32){
#pragma unroll
      for(int c=0;c<5;c++) AG[t*480+320+lane*5+c]=aQ[n*160+lane*5+c];
    }
  }
  __syncthreads();
  float su0[2],su1[2];
#pragma unroll
  for(int t=0;t<2;t++){ su0[t]=S[(size_t)(nb+t)*128+lane]; su1[t]=S[(size_t)(nb+t)*128+64+lane]; }
  for(int k=0;k<128;k++){
    float w0=Wos[k*128+lane], w1=Wos[k*128+64+lane];
#pragma unroll
    for(int t=0;t<2;t++){ float a=AG[t*480+k]; su0[t]=fmaf(a,w0,su0[t]); su1[t]=fmaf(a,w1,su1[t]); }
  }
  float vu[2][3];
#pragma unroll
  for(int t=0;t<2;t++){
#pragma unroll
    for(int c=0;c<3;c++) vu[t][c]=V[(size_t)(nb+t)*192+lane*3+c];
  }
  for(int j=0;j<64;j++){
    float w=Wov[j*64+lane];
#pragma unroll
    for(int t=0;t<2;t++){
#pragma unroll
      for(int c=0;c<3;c++) vu[t][c]=fmaf(AG[t*480+128+j*3+c],w,vu[t][c]);
    }
  }
  float qu[2][5];
#pragma unroll
  for(int t=0;t<2;t++){
#pragma unroll
    for(int c=0;c<5;c++) qu[t][c]=(lane<32)?Q[(size_t)(nb+t)*160+lane*5+c]:0.0f;
  }
  for(int j=0;j<32;j++){
    float w=(lane<32)?Woq[j*32+lane]:0.0f;
#pragma unroll
    for(int t=0;t<2;t++){
#pragma unroll
      for(int c=0;c<5;c++) qu[t][c]=fmaf(AG[t*480+320+j*5+c],w,qu[t][c]);
    }
  }
  for(int t=0;t<2;t++){
    size_t n=nb+t;
    S[n*128+lane]=su0[t];
    S[n*128+64+lane]=su1[t];
    float mu=wsum64(su0[t]+su1[t])*(1.0f/128.0f);
    float c0=su0[t]-mu, c1=su1[t]-mu;
    float var=wsum64(c0*c0+c1*c1)*(1.0f/128.0f);
    float rs=rsqrtf(var+1e-5f);
    Yb[n*480+lane]=c0*rs*g2s[lane];
    Yb[n*480+64+lane]=c1*rs*g2s[64+lane];
    float vx=vu[t][0], vy=vu[t][1], vz=vu[t][2];
    V[n*192+lane*3+0]=vx; V[n*192+lane*3+1]=vy; V[n*192+lane*3+2]=vz;
    float nv=wsum64(vx*vx+vy*vy+vz*vz)*(1.0f/64.0f);
    float rv=rsqrtf(nv+1e-5f)*g2v[lane];
    Yb[n*480+128+lane*3+0]=vx*rv;
    Yb[n*480+128+lane*3+1]=vy*rv;
    Yb[n*480+128+lane*3+2]=vz*rv;
    float qs=0;
    if(lane<32){
#pragma unroll
      for(int c=0;c<5;c++){ Q[n*160+lane*5+c]=qu[t][c]; qs+=qu[t][c]*qu[t][c]; }
    }
    float nq=wsum64(qs)*(1.0f/32.0f);
    float rq=rsqrtf(nq+1e-5f);
    if(lane<32){
      float g=g2q[lane]*rq;
#pragma unroll
      for(int c=0;c<5;c++) Yb[n*480+320+lane*5+c]=qu[t][c]*g;
    }
  }
}

// ---------------- ffn_b: gated FFN + residual (4w x 2n) -------------------------
__global__ __launch_bounds__(256) void k_ffn_b(
    float* __restrict__ S, float* __restrict__ V, float* __restrict__ Q,
    const float* __restrict__ Yb,
    const float* __restrict__ W1s, const float* __restrict__ W1gv, const float* __restrict__ W1gq,
    const float* __restrict__ W1v, const float* __restrict__ W1q,
    const float* __restrict__ W2s, const float* __restrict__ W2v, const float* __restrict__ W2q){
  int tid=threadIdx.x; int lane=tid&63; int wv=tid>>6;
  int nb=blockIdx.x*8+wv*2;
  __shared__ float AGall[4][2*480];
  float* AG=AGall[wv];
#pragma unroll
  for(int t=0;t<2;t++){
    size_t n=nb+t;
    AG[t*480+lane]=Yb[n*480+lane];
    AG[t*480+64+lane]=Yb[n*480+64+lane];
#pragma unroll
    for(int c=0;c<3;c++) AG[t*480+128+lane*3+c]=Yb[n*480+128+lane*3+c];
    if(lane<32){
#pragma unroll
      for(int c=0;c<5;c++) AG[t*480+320+lane*5+c]=Yb[n*480+320+lane*5+c];
    }
  }
  __syncthreads();
  float sm0[2],sm1[2],gvv[2],gqq[2];
#pragma unroll
  for(int t=0;t<2;t++){sm0[t]=0;sm1[t]=0;gvv[t]=0;gqq[t]=0;}
  for(int k=0;k<128;k++){
    float w0=W1s[k*128+lane], w1=W1s[k*128+64+lane];
    float wg=W1gv[k*64+lane];
    float wq=(lane<32)?W1gq[k*32+lane]:0.0f;
#pragma unroll
    for(int t=0;t<2;t++){
      float y=AG[t*480+k];
      sm0[t]=fmaf(y,w0,sm0[t]); sm1[t]=fmaf(y,w1,sm1[t]);
      gvv[t]=fmaf(y,wg,gvv[t]); gqq[t]=fmaf(y,wq,gqq[t]);
    }
  }
#pragma unroll
  for(int t=0;t<2;t++){
    sm0[t]=siluf(sm0[t]); sm1[t]=siluf(sm1[t]);
    gvv[t]=sigmf(gvv[t]); gqq[t]=sigmf(gqq[t]);
  }
  float vm[2][3];
#pragma unroll
  for(int t=0;t<2;t++){vm[t][0]=0;vm[t][1]=0;vm[t][2]=0;}
  for(int j=0;j<64;j++){
    float w=W1v[j*64+lane];
#pragma unroll
    for(int t=0;t<2;t++){
#pragma unroll
      for(int c=0;c<3;c++) vm[t][c]=fmaf(AG[t*480+128+j*3+c],w,vm[t][c]);
    }
  }
#pragma unroll
  for(int t=0;t<2;t++){
#pragma unroll
    for(int c=0;c<3;c++) vm[t][c]*=gvv[t];
  }
  float qm[2][5];
#pragma unroll
  for(int t=0;t<2;t++){
#pragma unroll
    for(int c=0;c<5;c++) qm[t][c]=0;
  }
  for(int j=0;j<32;j++){
    float w=(lane<32)?W1q[j*32+lane]:0.0f;
#pragma unroll
    for(int t=0;t<2;t++){
#pragma unroll
      for(int c=0;c<5;c++) qm[t][c]=fmaf(AG[t*480+320+j*5+c],w,qm[t][c]);
    }
  }
#pragma unroll
  for(int t=0;t<2;t++){
#pragma unroll
    for(int c=0;c<5;c++) qm[t][c]*=gqq[t];
  }
  __syncthreads();
#pragma unroll
  for(int t=0;t<2;t++){
    AG[t*480+lane]=sm0[t]; AG[t*480+64+lane]=sm1[t];
#pragma unroll
    for(int c=0;c<3;c++) AG[t*480+128+lane*3+c]=vm[t][c];
    if(lane<32){
#pragma unroll
      for(int c=0;c<5;c++) AG[t*480+320+lane*5+c]=qm[t][c];
    }
  }
  __syncthreads();
  float fs0[2],fs1[2];
#pragma unroll
  for(int t=0;t<2;t++){ fs0[t]=S[(size_t)(nb+t)*128+lane]; fs1[t]=S[(size_t)(nb+t)*128+64+lane]; }
  for(int k=0;k<128;k++){
    float w0=W2s[k*128+lane], w1=W2s[k*128+64+lane];
#pragma unroll
    for(int t=0;t<2;t++){ float a=AG[t*480+k]; fs0[t]=fmaf(a,w0,fs0[t]); fs1[t]=fmaf(a,w1,fs1[t]); }
  }
#pragma unroll
  for(int t=0;t<2;t++){
    S[(size_t)(nb+t)*128+lane]=fs0[t];
    S[(size_t)(nb+t)*128+64+lane]=fs1[t];
  }
  float fv2[2][3];
#pragma unroll
  for(int t=0;t<2;t++){
#pragma unroll
    for(int c=0;c<3;c++) fv2[t][c]=V[(size_t)(nb+t)*192+lane*3+c];
  }
  for(int j=0;j<64;j++){
    float w=W2v[j*64+lane];
#pragma unroll
    for(int t=0;t<2;t++){
#pragma unroll
      for(int c=0;c<3;c++) fv2[t][c]=fmaf(AG[t*480+128+j*3+c],w,fv2[t][c]);
    }
  }
#pragma unroll
  for(int t=0;t<2;t++){
#pragma unroll
    for(int c=0;c<3;c++) V[(size_t)(nb+t)*192+lane*3+c]=fv2[t][c];
  }
  float fq2[2][5];
#pragma unroll
  for(int t=0;t<2;t++){
#pragma unroll
    for(int c=0;c<5;c++) fq2[t][c]=(lane<32)?Q[(size_t)(nb+t)*160+lane*5+c]:0.0f;
  }
  for(int j=0;j<32;j++){
    float w=(lane<32)?W2q[j*32+lane]:0.0f;
#pragma unroll
    for(int t=0;t<2;t++){
#pragma unroll
      for(int c=0;c<5;c++) fq2[t][c]=fmaf(AG[t*480+320+j*5+c],w,fq2[t][c]);
    }
  }
  if(lane<32){
#pragma unroll
    for(int t=0;t<2;t++){
#pragma unroll
      for(int c=0;c<5;c++) Q[(size_t)(nb+t)*160+lane*5+c]=fq2[t][c];
    }
  }
}

// ---------------- output head (4 waves x 4 nodes) ----------------
__global__ __launch_bounds__(256) void k_head2(const float* __restrict__ S, const float* __restrict__ tt,
    const float* __restrict__ Wf, const float* __restrict__ lng, const float* __restrict__ lnb,
    const float* __restrict__ Wh1, const float* __restrict__ Wh2, float* __restrict__ out){
  int tid=threadIdx.x; int lane=tid&63; int wv=tid>>6;
  int nb=blockIdx.x*16+wv*4;
  __shared__ float SLall[4][4*128];
  __shared__ float FLall[4][4*512];
  float* SL=SLall[wv];
  float* FL=FLall[wv];
#pragma unroll
  for(int t=0;t<4;t++){
    SL[t*128+lane]=S[(size_t)(nb+t)*128+lane];
    SL[t*128+64+lane]=S[(size_t)(nb+t)*128+64+lane];
  }
  __syncthreads();
  float fa[4][8];
#pragma unroll
  for(int t=0;t<4;t++){
#pragma unroll
    for(int i=0;i<8;i++) fa[t][i]=0;
  }
  for(int k=0;k<128;k++){
    float w[8];
#pragma unroll
    for(int i=0;i<8;i++) w[i]=Wf[k*512+lane+64*i];
#pragma unroll
    for(int t=0;t<4;t++){
      float sv=SL[t*128+k];
#pragma unroll
      for(int i=0;i<8;i++) fa[t][i]=fmaf(sv,w[i],fa[t][i]);
    }
  }
#pragma unroll
  for(int t=0;t<4;t++){
    float part=0;
#pragma unroll
    for(int i=0;i<8;i++) part+=fa[t][i];
    float mu=wsum64(part)*(1.0f/512.0f);
    float var=0;
#pragma unroll
    for(int i=0;i<8;i++){ float c=fa[t][i]-mu; var+=c*c; }
    var=wsum64(var)*(1.0f/512.0f);
    float rs=rsqrtf(var+1e-5f);
#pragma unroll
    for(int i=0;i<8;i++){
      int col=lane+64*i;
      FL[t*512+col]=(fa[t][i]-mu)*rs*lng[col]+lnb[col];
    }
  }
  __syncthreads();
  float ha[4][8];
#pragma unroll
  for(int t=0;t<4;t++){
#pragma unroll
    for(int i=0;i<8;i++) ha[t][i]=0;
  }
  for(int k=0;k<512;k++){
    float w[8];
#pragma unroll
    for(int i=0;i<8;i++) w[i]=Wh1[k*512+lane+64*i];
#pragma unroll
    for(int t=0;t<4;t++){
      float f=FL[t*512+k];
#pragma unroll
      for(int i=0;i<8;i++) ha[t][i]=fmaf(f,w[i],ha[t][i]);
    }
  }
#pragma unroll
  for(int t=0;t<4;t++){
    float p0=0,p1=0,p2=0;
#pragma unroll
    for(int i=0;i<8;i++){
      float hc=siluf(ha[t][i]);
      int col=lane+64*i;
      p0=fmaf(hc,Wh2[col*3+0],p0);
      p1=fmaf(hc,Wh2[col*3+1],p1);
      p2=fmaf(hc,Wh2[col*3+2],p2);
    }
    p0=wsum64(p0); p1=wsum64(p1); p2=wsum64(p2);
    if(lane==0){
      int n=nb+t;
      float tv=tt[n];
      float lmc=-0.25f*tv*tv*19.9f-0.05f*tv;
      float sd=sqrtf(1.0f-__expf(2.0f*lmc));
      float sc=-1.0f/sd;
      out[n*3+0]=p0*sc; out[n*3+1]=p1*sc; out[n*3+2]=p2*sc;
    }
  }
}

extern "C" void kernel_launch(void* const* d_in, const int* in_sizes, int n_in,
                              void* d_out, int out_size, void* d_ws, size_t ws_size,
                              hipStream_t stream){
  const float* pos  =(const float*)d_in[0];
  const float* tt   =(const float*)d_in[1];
  const int*   fin  =(const int*)d_in[2];
  const int*   esrc =(const int*)d_in[4];
  const int*   edst =(const int*)d_in[5];
  const float* Wemb =(const float*)d_in[6];
  const float* Wr1  =(const float*)d_in[7];
  const float* Wr2  =(const float*)d_in[8];
  const float* Wr3  =(const float*)d_in[9];
  const float* g1s  =(const float*)d_in[10];
  const float* g1v  =(const float*)d_in[11];
  const float* g1q  =(const float*)d_in[12];
  const float* Wrad1=(const float*)d_in[13];
  const float* Wrad2=(const float*)d_in[14];
  const float* Ws   =(const float*)d_in[15];
  const float* Wsd  =(const float*)d_in[16];
  const float* Wsv  =(const float*)d_in[17];
  const float* Wsq  =(const float*)d_in[18];
  const float* Wv   =(const float*)d_in[19];
  const float* Wq   =(const float*)d_in[20];
  const float* Amat =(const float*)d_in[21];
  const float* Wos  =(const float*)d_in[22];
  const float* Wov  =(const float*)d_in[23];
  const float* Woq  =(const float*)d_in[24];
  const float* g2s  =(const float*)d_in[25];
  const float* g2v  =(const float*)d_in[26];
  const float* g2q  =(const float*)d_in[27];
  const float* W1s  =(const float*)d_in[28];
  const float* W1gv =(const float*)d_in[29];
  const float* W1gq =(const float*)d_in[30];
  const float* W1v  =(const float*)d_in[31];
  const float* W1q  =(const float*)d_in[32];
  const float* W2s  =(const float*)d_in[33];
  const float* W2v  =(const float*)d_in[34];
  const float* W2q  =(const float*)d_in[35];
  const float* Wf   =(const float*)d_in[36];
  const float* lng  =(const float*)d_in[37];
  const float* lnb  =(const float*)d_in[38];
  const float* Wh1  =(const float*)d_in[39];
  const float* Wh2  =(const float*)d_in[40];

  const int N=NNODE;
  const int E=in_sizes[4];
  const int Ec=E/2;

  char* p=(char*)d_ws;
  auto alloc=[&](size_t bytes)->void*{ void* r=(void*)p; p+=(bytes+255)&~(size_t)255; return r; };
  int*   row_start=(int*)alloc((size_t)(N+1)*4);
  int*   cnt      =(int*)alloc(4);
  int*   prank    =(int*)alloc((size_t)E*4);
  float* dist     =(float*)alloc((size_t)E*4);
  float* sh       =(float*)alloc((size_t)E*8*4);
  float* cdist    =(float*)alloc((size_t)Ec*4);
  float* rbf      =(float*)alloc((size_t)Ec*128*4);
  float* dwwr     =(float*)alloc((size_t)Ec*320*4);
  float* S        =(float*)alloc((size_t)N*128*4);
  float* V        =(float*)alloc((size_t)N*192*4);
  float* Q        =(float*)alloc((size_t)N*160*4);
  float* Pa       =(float*)alloc((size_t)N*128*4);
  float* Pb       =(float*)alloc((size_t)N*128*4);
  float* Pc       =(float*)alloc((size_t)N*64*4);
  float* Pd       =(float*)alloc((size_t)N*32*4);
  float* PVb      =(float*)alloc((size_t)N*192*4);
  float* PQb      =(float*)alloc((size_t)N*160*4);
  float* aSb      =(float*)alloc((size_t)N*128*4);
  float* aVb      =(float*)alloc((size_t)N*192*4);
  float* aQb      =(float*)alloc((size_t)N*160*4);
  float* Yb       =(float*)alloc((size_t)N*480*4);

  k_csr<<<(N+1+255)/256,256,0,stream>>>(esrc,E,N,row_start);
  k_geom<<<(E+255)/256,256,0,stream>>>(pos,esrc,edst,E,dist,sh);
  hipMemsetAsync(cnt,0,4,stream);
  k_rank1<<<(E+255)/256,256,0,stream>>>(esrc,edst,dist,E,Ec,cnt,prank,cdist);
  k_rank2<<<(E+255)/256,256,0,stream>>>(esrc,edst,row_start,E,prank);
  k_rbf<<<(Ec*128+255)/256,256,0,stream>>>(cdist,Ec,rbf);
  k_dw3<<<(Ec+63)/64,256,0,stream>>>(rbf,Ec,Wr1,Wr2,Wr3,dwwr);
  k_nodeinit<<<N,64,0,stream>>>(tt,fin,Wemb,row_start,prank,sh,dwwr,S,V,Q);

  for(int i=0;i<6;i++){
    k_nodemm<<<N/8,256,0,stream>>>(S,V,Q,
        g1s+(size_t)i*128, g1v+(size_t)i*64, g1q+(size_t)i*32,
        Ws+(size_t)i*16384, Wsd+(size_t)i*16384, Wsv+(size_t)i*8192,
        Wsq+(size_t)i*4096, Wv+(size_t)i*4096, Wq+(size_t)i*1024,
        Pa,Pb,Pc,Pd,PVb,PQb);
    k_wr2<<<(Ec+31)/32,256,0,stream>>>(rbf,Ec,
        Wrad1+(size_t)i*8192, Wrad2+(size_t)i*20480, dwwr);
    k_attn<<<N,64,0,stream>>>(row_start,edst,prank,sh,dwwr,
        Pa,Pb,Pc,Pd,PVb,PQb, Amat+(size_t)i*128, aSb,aVb,aQb);
    k_ffn_a<<<N/8,256,0,stream>>>(S,V,Q,aSb,aVb,aQb,
        Wos+(size_t)i*16384, Wov+(size_t)i*4096, Woq+(size_t)i*1024,
        g2s+(size_t)i*128, g2v+(size_t)i*64, g2q+(size_t)i*32, Yb);
    k_ffn_b<<<N/8,256,0,stream>>>(S,V,Q,Yb,
        W1s+(size_t)i*16384, W1gv+(size_t)i*8192, W1gq+(size_t)i*4096,
        W1v+(size_t)i*4096, W1q+(size_t)i*1024,
        W2s+(size_t)i*16384, W2v+(size_t)i*4096, W2q+(size_t)i*1024);
  }
  k_head2<<<N/16,256,0,stream>>>(S,tt,Wf,lng,lnb,Wh1,Wh2,(float*)d_out);
}

// Round 9
// 3258.903 us; speedup vs baseline: 1.9112x; 1.9112x over previous
//
#include <hip/hip_runtime.h>
#include <math.h>

#define DEV __device__ __forceinline__

constexpr int NNODE = 8192;

DEV float wsum64(float x){
#pragma unroll
  for(int m=32;m>=1;m>>=1) x += __shfl_xor(x,m,64);
  return x;
}
DEV float siluf(float x){ return x/(1.0f+__expf(-x)); }
DEV float sigmf(float x){ return 1.0f/(1.0f+__expf(-x)); }
DEV float lreluf(float x){ return x>0.0f ? x : 0.2f*x; }
DEV float pick4(float a0,float a1,float a2,float a3,int h){
  float x=(h&1)?a1:a0;
  float y=(h&1)?a3:a2;
  return (h&2)?y:x;
}

// ---------------- CSR build ----------------
__global__ void k_csr(const int* __restrict__ esrc, int E, int N, int* __restrict__ row_start){
  int n = blockIdx.x*blockDim.x + threadIdx.x;
  if(n > N) return;
  int lo=0, hi=E;
  while(lo<hi){ int mid=(lo+hi)>>1; if(esrc[mid] < n) lo=mid+1; else hi=mid; }
  row_start[n]=lo;
}

// ---------------- per directed edge: dist + spherical harmonics ----------------
__global__ void k_geom(const float* __restrict__ pos, const int* __restrict__ esrc,
                       const int* __restrict__ edst, int E,
                       float* __restrict__ dist, float* __restrict__ sh){
  int e = blockIdx.x*blockDim.x + threadIdx.x;
  if(e>=E) return;
  int a=esrc[e], b=edst[e];
  float x=pos[3*a+0]-pos[3*b+0];
  float y=pos[3*a+1]-pos[3*b+1];
  float z=pos[3*a+2]-pos[3*b+2];
  float d=sqrtf(x*x+y*y+z*z);
  dist[e]=d;
  float id=1.0f/(d+1e-9f);
  float ux=x*id, uy=y*id, uz=z*id;
  const float s3=1.7320508075688772f, c15=3.872983346207417f, c5=2.23606797749979f;
  float* o = sh + (size_t)e*8;
  o[0]=s3*uy; o[1]=s3*uz; o[2]=s3*ux;
  o[3]=c15*ux*uy; o[4]=c15*uy*uz; o[5]=0.5f*c5*(3.0f*uz*uz-1.0f);
  o[6]=c15*ux*uz; o[7]=0.5f*c15*(ux*ux-uy*uy);
}

// ---------------- canonical pair ranking ----------------
__global__ void k_rank1(const int* __restrict__ esrc, const int* __restrict__ edst,
                        const float* __restrict__ dist, int E, int Ec,
                        int* __restrict__ cnt, int* __restrict__ prank, float* __restrict__ cdist){
  int e = blockIdx.x*blockDim.x + threadIdx.x;
  if(e>=E) return;
  int sn=esrc[e], dn=edst[e];
  if(sn<dn){
    int r=atomicAdd(cnt,1);
    if(r<Ec){ prank[e]=r; cdist[r]=dist[e]; } else prank[e]=0;
  }
}
__global__ void k_rank2(const int* __restrict__ esrc, const int* __restrict__ edst,
                        const int* __restrict__ row_start, int E, int* __restrict__ prank){
  int e = blockIdx.x*blockDim.x + threadIdx.x;
  if(e>=E) return;
  int sn=esrc[e], dn=edst[e];
  if(sn>dn){
    int lo=row_start[dn], hi=row_start[dn+1];
    while(lo<hi){ int mid=(lo+hi)>>1; if(edst[mid]<sn) lo=mid+1; else hi=mid; }
    prank[e]=prank[lo];
  }
}

// ---------------- rbf precompute ----------------
__global__ void k_rbf(const float* __restrict__ cdist, int Ec, float* __restrict__ rbf){
  int idx = blockIdx.x*blockDim.x + threadIdx.x;
  if(idx >= Ec*128) return;
  int e=idx>>7, k=idx&127;
  float d=cdist[e];
  float ck=(30.0f/127.0f)*(float)k;
  float dt=d-ck;
  const float gamma = 0.5f/((30.0f/128.0f)*(30.0f/128.0f));
  rbf[idx]=__expf(-gamma*dt*dt);
}

// ---------------- radial MLP per layer (32 edges/block) ----------------
__global__ __launch_bounds__(256) void k_wr2(const float* __restrict__ rbf, int Ec,
    const float* __restrict__ W1, const float* __restrict__ W2, float* __restrict__ wr){
  __shared__ float RB[32][132];
  __shared__ float H[32][72];
  int tid=threadIdx.x;
  int base=blockIdx.x*32;
#pragma unroll
  for(int i=0;i<16;i++){
    int idx=tid+256*i;
    int r=idx>>7, c=idx&127;
    RB[r][c]=(base+r<Ec)? rbf[(size_t)(base+r)*128+c] : 0.0f;
  }
  __syncthreads();
  int j=tid&63, g=tid>>6;
  int eg=g*8;
  float acc[8];
#pragma unroll
  for(int e=0;e<8;e++) acc[e]=0.0f;
  for(int k=0;k<128;k+=4){
    float w0=W1[k*64+j], w1=W1[(k+1)*64+j], w2=W1[(k+2)*64+j], w3=W1[(k+3)*64+j];
#pragma unroll
    for(int e=0;e<8;e++){
      const float4 rv=*reinterpret_cast<const float4*>(&RB[eg+e][k]);
      acc[e]=fmaf(rv.x,w0,acc[e]); acc[e]=fmaf(rv.y,w1,acc[e]);
      acc[e]=fmaf(rv.z,w2,acc[e]); acc[e]=fmaf(rv.w,w3,acc[e]);
    }
  }
#pragma unroll
  for(int e=0;e<8;e++) H[eg+e][j]=siluf(acc[e]);
  __syncthreads();
  for(int c0=0;c0<320;c0+=64){
    float a2[8];
#pragma unroll
    for(int e=0;e<8;e++) a2[e]=0.0f;
    for(int k=0;k<64;k+=4){
      float w0=W2[k*320+c0+j], w1=W2[(k+1)*320+c0+j], w2=W2[(k+2)*320+c0+j], w3=W2[(k+3)*320+c0+j];
#pragma unroll
      for(int e=0;e<8;e++){
        const float4 hv=*reinterpret_cast<const float4*>(&H[eg+e][k]);
        a2[e]=fmaf(hv.x,w0,a2[e]); a2[e]=fmaf(hv.y,w1,a2[e]);
        a2[e]=fmaf(hv.z,w2,a2[e]); a2[e]=fmaf(hv.w,w3,a2[e]);
      }
    }
#pragma unroll
    for(int e=0;e<8;e++){
      if(base+eg+e<Ec) wr[(size_t)(base+eg+e)*320+c0+j]=a2[e];
    }
  }
}

// ---------------- init edge MLP ----------------
__global__ __launch_bounds__(256) void k_dw3(const float* __restrict__ rbf, int Ec,
    const float* __restrict__ W1, const float* __restrict__ W2, const float* __restrict__ W3,
    float* __restrict__ dw){
  __shared__ float RB[64][132];
  __shared__ float H1[64][72];
  __shared__ float H2[64][72];
  int tid=threadIdx.x;
  int base=blockIdx.x*64;
#pragma unroll
  for(int i=0;i<32;i++){
    int idx=tid+256*i;
    int r=idx>>7, c=idx&127;
    RB[r][c]=(base+r<Ec)? rbf[(size_t)(base+r)*128+c] : 0.0f;
  }
  __syncthreads();
  int j=tid&63, g=tid>>6;
  int e0=g*16;
  float acc[16];
#pragma unroll
  for(int e=0;e<16;e++) acc[e]=0.0f;
  for(int k=0;k<128;k+=4){
    float w0=W1[k*64+j], w1=W1[(k+1)*64+j], w2=W1[(k+2)*64+j], w3=W1[(k+3)*64+j];
#pragma unroll
    for(int e=0;e<16;e++){
      const float4 rv=*reinterpret_cast<const float4*>(&RB[e0+e][k]);
      acc[e]=fmaf(rv.x,w0,acc[e]); acc[e]=fmaf(rv.y,w1,acc[e]);
      acc[e]=fmaf(rv.z,w2,acc[e]); acc[e]=fmaf(rv.w,w3,acc[e]);
    }
  }
#pragma unroll
  for(int e=0;e<16;e++) H1[e0+e][j]=siluf(acc[e]);
  __syncthreads();
#pragma unroll
  for(int e=0;e<16;e++) acc[e]=0.0f;
  for(int k=0;k<64;k+=4){
    float w0=W2[k*64+j], w1=W2[(k+1)*64+j], w2=W2[(k+2)*64+j], w3=W2[(k+3)*64+j];
#pragma unroll
    for(int e=0;e<16;e++){
      const float4 hv=*reinterpret_cast<const float4*>(&H1[e0+e][k]);
      acc[e]=fmaf(hv.x,w0,acc[e]); acc[e]=fmaf(hv.y,w1,acc[e]);
      acc[e]=fmaf(hv.z,w2,acc[e]); acc[e]=fmaf(hv.w,w3,acc[e]);
    }
  }
#pragma unroll
  for(int e=0;e<16;e++) H2[e0+e][j]=siluf(acc[e]);
  __syncthreads();
  for(int c0=0;c0<224;c0+=64){
    int c=c0+j;
    bool ok = c<224;
    int cc = ok? c : 0;
    float a2[16];
#pragma unroll
    for(int e=0;e<16;e++) a2[e]=0.0f;
    for(int k=0;k<64;k+=4){
      float w0=W3[k*224+cc], w1=W3[(k+1)*224+cc], w2=W3[(k+2)*224+cc], w3=W3[(k+3)*224+cc];
#pragma unroll
      for(int e=0;e<16;e++){
        const float4 hv=*reinterpret_cast<const float4*>(&H2[e0+e][k]);
        a2[e]=fmaf(hv.x,w0,a2[e]); a2[e]=fmaf(hv.y,w1,a2[e]);
        a2[e]=fmaf(hv.z,w2,a2[e]); a2[e]=fmaf(hv.w,w3,a2[e]);
      }
    }
#pragma unroll
    for(int e=0;e<16;e++){
      if(ok && base+e0+e<Ec) dw[(size_t)(base+e0+e)*224+c]=a2[e];
    }
  }
}

// ---------------- node init ----------------
__global__ __launch_bounds__(64) void k_nodeinit(const float* __restrict__ tt, const int* __restrict__ fin,
    const float* __restrict__ Wemb, const int* __restrict__ row_start, const int* __restrict__ prank,
    const float* __restrict__ sh, const float* __restrict__ dw,
    float* __restrict__ S, float* __restrict__ V, float* __restrict__ Q){
  int n=blockIdx.x, lane=threadIdx.x;
  __shared__ float te[64];
  float tn=tt[n];
  if(lane<32){
    float fr=__expf(-9.210340371976184f*((float)lane/32.0f));
    float ang=tn*10000.0f*fr;
    te[lane]=sinf(ang);
    te[32+lane]=cosf(ang);
  }
  __syncthreads();
  int f=fin[n];
  float s0=Wemb[f*128+lane], s1=Wemb[f*128+64+lane];
  for(int j=0;j<64;j++){
    float tb=te[j];
    s0=fmaf(tb,Wemb[(20+j)*128+lane],s0);
    s1=fmaf(tb,Wemb[(20+j)*128+64+lane],s1);
  }
  float aS0=0,aS1=0,aV0=0,aV1=0,aV2=0,aQ0=0,aQ1=0,aQ2=0,aQ3=0,aQ4=0;
  int e0=row_start[n], e1=row_start[n+1];
  for(int e=e0;e<e1;e++){
    const float* de = dw + (size_t)prank[e]*224;
    const float* se = sh + (size_t)e*8;
    aS0+=de[lane]; aS1+=de[64+lane];
    float w1=de[128+lane];
    aV0=fmaf(w1,-se[0],aV0); aV1=fmaf(w1,-se[1],aV1); aV2=fmaf(w1,-se[2],aV2);
    if(lane<32){
      float w2=de[192+lane];
      aQ0=fmaf(w2,se[3],aQ0); aQ1=fmaf(w2,se[4],aQ1); aQ2=fmaf(w2,se[5],aQ2);
      aQ3=fmaf(w2,se[6],aQ3); aQ4=fmaf(w2,se[7],aQ4);
    }
  }
  const float inv = 1.0f/sqrtf(15.57930850982666f);
  S[(size_t)n*128+lane]=s0+inv*aS0;
  S[(size_t)n*128+64+lane]=s1+inv*aS1;
  V[(size_t)n*192+lane*3+0]=inv*aV0;
  V[(size_t)n*192+lane*3+1]=inv*aV1;
  V[(size_t)n*192+lane*3+2]=inv*aV2;
  if(lane<32){
    Q[(size_t)n*160+lane*5+0]=inv*aQ0;
    Q[(size_t)n*160+lane*5+1]=inv*aQ1;
    Q[(size_t)n*160+lane*5+2]=inv*aQ2;
    Q[(size_t)n*160+lane*5+3]=inv*aQ3;
    Q[(size_t)n*160+lane*5+4]=inv*aQ4;
  }
}

// ---------------- eq_ln(g1) + per-node projections (4 waves x 4 nodes) ----------
__global__ __launch_bounds__(256) void k_nodemm(
    const float* __restrict__ S, const float* __restrict__ V, const float* __restrict__ Q,
    const float* __restrict__ g1s, const float* __restrict__ g1v, const float* __restrict__ g1q,
    const float* __restrict__ Ws, const float* __restrict__ Wsd, const float* __restrict__ Wsv,
    const float* __restrict__ Wsq, const float* __restrict__ Wv, const float* __restrict__ Wq,
    float* __restrict__ Pa, float* __restrict__ Pb, float* __restrict__ Pc, float* __restrict__ Pd,
    float* __restrict__ PVb, float* __restrict__ PQb){
  int tid=threadIdx.x; int lane=tid&63; int wv=tid>>6;
  int nb=blockIdx.x*16+wv*4;
  __shared__ float Yall[4][4*480];
  float* Y=Yall[wv];
  for(int t=0;t<4;t++){
    int n=nb+t;
    float s0=S[(size_t)n*128+lane], s1=S[(size_t)n*128+64+lane];
    float mu=wsum64(s0+s1)*(1.0f/128.0f);
    float c0=s0-mu, c1=s1-mu;
    float var=wsum64(c0*c0+c1*c1)*(1.0f/128.0f);
    float rs=rsqrtf(var+1e-5f);
    Y[t*480+lane]=c0*rs*g1s[lane];
    Y[t*480+64+lane]=c1*rs*g1s[64+lane];
    float vx=V[(size_t)n*192+lane*3+0], vy=V[(size_t)n*192+lane*3+1], vz=V[(size_t)n*192+lane*3+2];
    float nv=wsum64(vx*vx+vy*vy+vz*vz)*(1.0f/64.0f);
    float rv=rsqrtf(nv+1e-5f)*g1v[lane];
    Y[t*480+128+lane*3+0]=vx*rv;
    Y[t*480+128+lane*3+1]=vy*rv;
    Y[t*480+128+lane*3+2]=vz*rv;
    float q0=0,q1=0,q2=0,q3=0,q4=0,qs=0;
    if(lane<32){
      q0=Q[(size_t)n*160+lane*5+0]; q1=Q[(size_t)n*160+lane*5+1]; q2=Q[(size_t)n*160+lane*5+2];
      q3=Q[(size_t)n*160+lane*5+3]; q4=Q[(size_t)n*160+lane*5+4];
      qs=q0*q0+q1*q1+q2*q2+q3*q3+q4*q4;
    }
    float nq=wsum64(qs)*(1.0f/32.0f);
    float rq=rsqrtf(nq+1e-5f);
    if(lane<32){
      float g=g1q[lane]*rq;
      Y[t*480+320+lane*5+0]=q0*g; Y[t*480+320+lane*5+1]=q1*g; Y[t*480+320+lane*5+2]=q2*g;
      Y[t*480+320+lane*5+3]=q3*g; Y[t*480+320+lane*5+4]=q4*g;
    }
  }
  __syncthreads();
  float pa0[4],pa1[4],pb0[4],pb1[4];
#pragma unroll
  for(int t=0;t<4;t++){pa0[t]=0;pa1[t]=0;pb0[t]=0;pb1[t]=0;}
#pragma unroll 4
  for(int k=0;k<128;k++){
    float wa0=Ws[k*128+lane], wa1=Ws[k*128+64+lane];
    float wb0=Wsd[k*128+lane], wb1=Wsd[k*128+64+lane];
#pragma unroll
    for(int t=0;t<4;t++){
      float y=Y[t*480+k];
      pa0[t]=fmaf(y,wa0,pa0[t]); pa1[t]=fmaf(y,wa1,pa1[t]);
      pb0[t]=fmaf(y,wb0,pb0[t]); pb1[t]=fmaf(y,wb1,pb1[t]);
    }
  }
#pragma unroll
  for(int t=0;t<4;t++){
    size_t n=nb+t;
    Pa[n*128+lane]=pa0[t]; Pa[n*128+64+lane]=pa1[t];
    Pb[n*128+lane]=pb0[t]; Pb[n*128+64+lane]=pb1[t];
  }
  float pc[4],pd[4];
#pragma unroll
  for(int t=0;t<4;t++){pc[t]=0;pd[t]=0;}
#pragma unroll 4
  for(int k=0;k<128;k++){
    float wc=Wsv[k*64+lane];
    float wd=(lane<32)?Wsq[k*32+lane]:0.0f;
#pragma unroll
    for(int t=0;t<4;t++){
      float y=Y[t*480+k];
      pc[t]=fmaf(y,wc,pc[t]); pd[t]=fmaf(y,wd,pd[t]);
    }
  }
#pragma unroll
  for(int t=0;t<4;t++){
    size_t n=nb+t;
    Pc[n*64+lane]=pc[t];
    if(lane<32) Pd[n*32+lane]=pd[t];
  }
  float pV[4][3];
#pragma unroll
  for(int t=0;t<4;t++){pV[t][0]=0;pV[t][1]=0;pV[t][2]=0;}
#pragma unroll 4
  for(int j=0;j<64;j++){
    float w=Wv[j*64+lane];
#pragma unroll
    for(int t=0;t<4;t++){
#pragma unroll
      for(int c=0;c<3;c++) pV[t][c]=fmaf(Y[t*480+128+j*3+c],w,pV[t][c]);
    }
  }
#pragma unroll
  for(int t=0;t<4;t++){
    size_t n=nb+t;
#pragma unroll
    for(int c=0;c<3;c++) PVb[n*192+lane*3+c]=pV[t][c];
  }
  float pQ[4][5];
#pragma unroll
  for(int t=0;t<4;t++){
#pragma unroll
    for(int c=0;c<5;c++) pQ[t][c]=0;
  }
#pragma unroll 4
  for(int j=0;j<32;j++){
    float w=(lane<32)?Wq[j*32+lane]:0.0f;
#pragma unroll
    for(int t=0;t<4;t++){
#pragma unroll
      for(int c=0;c<5;c++) pQ[t][c]=fmaf(Y[t*480+320+j*5+c],w,pQ[t][c]);
    }
  }
  if(lane<32){
#pragma unroll
    for(int t=0;t<4;t++){
      size_t n=nb+t;
#pragma unroll
      for(int c=0;c<5;c++) PQb[n*160+lane*5+c]=pQ[t][c];
    }
  }
}

// ---------------- attention: single-chain online segment-softmax ----------------
__global__ __launch_bounds__(64) void k_attn(
    const int* __restrict__ row_start, const int* __restrict__ edst, const int* __restrict__ prank,
    const float* __restrict__ sh, const float* __restrict__ wr,
    const float* __restrict__ Pa, const float* __restrict__ Pb, const float* __restrict__ Pc,
    const float* __restrict__ Pd, const float* __restrict__ PVb, const float* __restrict__ PQb,
    const float* __restrict__ Amat,
    float* __restrict__ aS, float* __restrict__ aV, float* __restrict__ aQ){
  int n=blockIdx.x, lane=threadIdx.x;
  int e0=row_start[n], e1=row_start[n+1];
  float b0=Pb[(size_t)n*128+lane], b1=Pb[(size_t)n*128+64+lane];
  int d5=lane>>5;
  float A0=Amat[d5*32+(lane&31)];
  float A1=Amat[(2+d5)*32+(lane&31)];
  int hv=lane>>4;
  int hq=(lane&31)>>3;
  float M0=-1e30f,M1=-1e30f,M2=-1e30f,M3=-1e30f;
  float D0=0,D1=0,D2=0,D3=0;
  float s0a=0,s1a=0,v0a=0,v1a=0,v2a=0,q0a=0,q1a=0,q2a=0,q3a=0,q4a=0;
  for(int e=e0;e<e1;e++){
    int m=edst[e];
    const float* wre = wr + (size_t)prank[e]*320;
    const float* se  = sh + (size_t)e*8;
    float ms0=(Pa[(size_t)m*128+lane]+b0)*wre[lane];
    float ms1=(Pa[(size_t)m*128+64+lane]+b1)*wre[64+lane];
    float l0=lreluf(ms0)*A0;
    float l1=lreluf(ms1)*A1;
#pragma unroll
    for(int mk=16;mk>=1;mk>>=1){ l0+=__shfl_xor(l0,mk,32); l1+=__shfl_xor(l1,mk,32); }
    float lg0=__shfl(l0,0,64), lg1=__shfl(l0,32,64);
    float lg2=__shfl(l1,0,64), lg3=__shfl(l1,32,64);
    float Mn,f0_,f1_,f2_,f3_,e0_,e1_,e2_,e3_;
    Mn=fmaxf(M0,lg0); f0_=__expf(M0-Mn); e0_=__expf(lg0-Mn); D0=D0*f0_+e0_; M0=Mn;
    Mn=fmaxf(M1,lg1); f1_=__expf(M1-Mn); e1_=__expf(lg1-Mn); D1=D1*f1_+e1_; M1=Mn;
    Mn=fmaxf(M2,lg2); f2_=__expf(M2-Mn); e2_=__expf(lg2-Mn); D2=D2*f2_+e2_; M2=Mn;
    Mn=fmaxf(M3,lg3); f3_=__expf(M3-Mn); e3_=__expf(lg3-Mn); D3=D3*f3_+e3_; M3=Mn;
    float fs0=d5?f1_:f0_, es0=d5?e1_:e0_;
    float fs1=d5?f3_:f2_, es1=d5?e3_:e2_;
    s0a=s0a*fs0+es0*ms0;
    s1a=s1a*fs1+es1*ms1;
    float fv=pick4(f0_,f1_,f2_,f3_,hv), ev=pick4(e0_,e1_,e2_,e3_,hv);
    float aw1a=wre[128+lane], aw1b=wre[192+lane];
    float t1=Pc[(size_t)m*64+lane]*aw1a;
    float mv0=fmaf(PVb[(size_t)m*192+lane*3+0],aw1b,-t1*se[0]);
    float mv1=fmaf(PVb[(size_t)m*192+lane*3+1],aw1b,-t1*se[1]);
    float mv2=fmaf(PVb[(size_t)m*192+lane*3+2],aw1b,-t1*se[2]);
    v0a=v0a*fv+ev*mv0; v1a=v1a*fv+ev*mv1; v2a=v2a*fv+ev*mv2;
    if(lane<32){
      float fq=pick4(f0_,f1_,f2_,f3_,hq), eq=pick4(e0_,e1_,e2_,e3_,hq);
      float aw2a=wre[256+lane], aw2b=wre[288+lane];
      float t2=Pd[(size_t)m*32+lane]*aw2a;
      float mq0=fmaf(PQb[(size_t)m*160+lane*5+0],aw2b,t2*se[3]);
      float mq1=fmaf(PQb[(size_t)m*160+lane*5+1],aw2b,t2*se[4]);
      float mq2=fmaf(PQb[(size_t)m*160+lane*5+2],aw2b,t2*se[5]);
      float mq3=fmaf(PQb[(size_t)m*160+lane*5+3],aw2b,t2*se[6]);
      float mq4=fmaf(PQb[(size_t)m*160+lane*5+4],aw2b,t2*se[7]);
      q0a=q0a*fq+eq*mq0; q1a=q1a*fq+eq*mq1; q2a=q2a*fq+eq*mq2;
      q3a=q3a*fq+eq*mq3; q4a=q4a*fq+eq*mq4;
    }
  }
  float Ds0=d5?D1:D0, Ds1=d5?D3:D2;
  aS[(size_t)n*128+lane]=s0a/(Ds0+1e-9f);
  aS[(size_t)n*128+64+lane]=s1a/(Ds1+1e-9f);
  float Dv=pick4(D0,D1,D2,D3,hv);
  float iv=1.0f/(Dv+1e-9f);
  aV[(size_t)n*192+lane*3+0]=v0a*iv;
  aV[(size_t)n*192+lane*3+1]=v1a*iv;
  aV[(size_t)n*192+lane*3+2]=v2a*iv;
  if(lane<32){
    float Dq=pick4(D0,D1,D2,D3,hq);
    float iq=1.0f/(Dq+1e-9f);
    aQ[(size_t)n*160+lane*5+0]=q0a*iq;
    aQ[(size_t)n*160+lane*5+1]=q1a*iq;
    aQ[(size_t)n*160+lane*5+2]=q2a*iq;
    aQ[(size_t)n*160+lane*5+3]=q3a*iq;
    aQ[(size_t)n*160+lane*5+4]=q4a*iq;
  }
}

// ---------------- ffn_a: attn-out proj + residual + eq_ln(g2) (4w x 4n) ---------
__global__ __launch_bounds__(256) void k_ffn_a(
    float* __restrict__ S, float* __restrict__ V, float* __restrict__ Q,
    const float* __restrict__ aS, const float* __restrict__ aV, const float* __restrict__ aQ,
    const float* __restrict__ Wos, const float* __restrict__ Wov, const float* __restrict__ Woq,
    const float* __restrict__ g2s, const float* __restrict__ g2v, const float* __restrict__ g2q,
    float* __restrict__ Yb){
  int tid=threadIdx.x; int lane=tid&63; int wv=tid>>6;
  int nb=blockIdx.x*16+wv*4;
  __shared__ float AGall[4][4*480];
  float* AG=AGall[wv];
#pragma unroll
  for(int t=0;t<4;t++){
    size_t n=nb+t;
    AG[t*480+lane]=aS[n*128+lane];
    AG[t*480+64+lane]=aS[n*128+64+lane];
#pragma unroll
    for(int c=0;c<3;c++) AG[t*480+128+lane*3+c]=aV[n*192+lane*3+c];
    if(lane<32){
#pragma unroll
      for(int c=0;c<5;c++) AG[t*480+320+lane*5+c]=aQ[n*160+lane*5+c];
    }
  }
  __syncthreads();
  float su0[4],su1[4];
#pragma unroll
  for(int t=0;t<4;t++){ su0[t]=S[(size_t)(nb+t)*128+lane]; su1[t]=S[(size_t)(nb+t)*128+64+lane]; }
#pragma unroll 4
  for(int k=0;k<128;k++){
    float w0=Wos[k*128+lane], w1=Wos[k*128+64+lane];
#pragma unroll
    for(int t=0;t<4;t++){ float a=AG[t*480+k]; su0[t]=fmaf(a,w0,su0[t]); su1[t]=fmaf(a,w1,su1[t]); }
  }
  float vu[4][3];
#pragma unroll
  for(int t=0;t<4;t++){
#pragma unroll
    for(int c=0;c<3;c++) vu[t][c]=V[(size_t)(nb+t)*192+lane*3+c];
  }
#pragma unroll 4
  for(int j=0;j<64;j++){
    float w=Wov[j*64+lane];
#pragma unroll
    for(int t=0;t<4;t++){
#pragma unroll
      for(int c=0;c<3;c++) vu[t][c]=fmaf(AG[t*480+128+j*3+c],w,vu[t][c]);
    }
  }
  float qu[4][5];
#pragma unroll
  for(int t=0;t<4;t++){
#pragma unroll
    for(int c=0;c<5;c++) qu[t][c]=(lane<32)?Q[(size_t)(nb+t)*160+lane*5+c]:0.0f;
  }
#pragma unroll 4
  for(int j=0;j<32;j++){
    float w=(lane<32)?Woq[j*32+lane]:0.0f;
#pragma unroll
    for(int t=0;t<4;t++){
#pragma unroll
      for(int c=0;c<5;c++) qu[t][c]=fmaf(AG[t*480+320+j*5+c],w,qu[t][c]);
    }
  }
  for(int t=0;t<4;t++){
    size_t n=nb+t;
    S[n*128+lane]=su0[t];
    S[n*128+64+lane]=su1[t];
    float mu=wsum64(su0[t]+su1[t])*(1.0f/128.0f);
    float c0=su0[t]-mu, c1=su1[t]-mu;
    float var=wsum64(c0*c0+c1*c1)*(1.0f/128.0f);
    float rs=rsqrtf(var+1e-5f);
    Yb[n*480+lane]=c0*rs*g2s[lane];
    Yb[n*480+64+lane]=c1*rs*g2s[64+lane];
    float vx=vu[t][0], vy=vu[t][1], vz=vu[t][2];
    V[n*192+lane*3+0]=vx; V[n*192+lane*3+1]=vy; V[n*192+lane*3+2]=vz;
    float nv=wsum64(vx*vx+vy*vy+vz*vz)*(1.0f/64.0f);
    float rv=rsqrtf(nv+1e-5f)*g2v[lane];
    Yb[n*480+128+lane*3+0]=vx*rv;
    Yb[n*480+128+lane*3+1]=vy*rv;
    Yb[n*480+128+lane*3+2]=vz*rv;
    float qs=0;
    if(lane<32){
#pragma unroll
      for(int c=0;c<5;c++){ Q[n*160+lane*5+c]=qu[t][c]; qs+=qu[t][c]*qu[t][c]; }
    }
    float nq=wsum64(qs)*(1.0f/32.0f);
    float rq=rsqrtf(nq+1e-5f);
    if(lane<32){
      float g=g2q[lane]*rq;
#pragma unroll
      for(int c=0;c<5;c++) Yb[n*480+320+lane*5+c]=qu[t][c]*g;
    }
  }
}

// ---------------- ffn_b: gated FFN + residual (4w x 4n) -------------------------
__global__ __launch_bounds__(256) void k_ffn_b(
    float* __restrict__ S, float* __restrict__ V, float* __restrict__ Q,
    const float* __restrict__ Yb,
    const float* __restrict__ W1s, const float* __restrict__ W1gv, const float* __restrict__ W1gq,
    const float* __restrict__ W1v, const float* __restrict__ W1q,
    const float* __restrict__ W2s, const float* __restrict__ W2v, const float* __restrict__ W2q){
  int tid=threadIdx.x; int lane=tid&63; int wv=tid>>6;
  int nb=blockIdx.x*16+wv*4;
  __shared__ float AGall[4][4*480];
  float* AG=AGall[wv];
#pragma unroll
  for(int t=0;t<4;t++){
    size_t n=nb+t;
    AG[t*480+lane]=Yb[n*480+lane];
    AG[t*480+64+lane]=Yb[n*480+64+lane];
#pragma unroll
    for(int c=0;c<3;c++) AG[t*480+128+lane*3+c]=Yb[n*480+128+lane*3+c];
    if(lane<32){
#pragma unroll
      for(int c=0;c<5;c++) AG[t*480+320+lane*5+c]=Yb[n*480+320+lane*5+c];
    }
  }
  __syncthreads();
  float sm0[4],sm1[4],gvv[4],gqq[4];
#pragma unroll
  for(int t=0;t<4;t++){sm0[t]=0;sm1[t]=0;gvv[t]=0;gqq[t]=0;}
#pragma unroll 4
  for(int k=0;k<128;k++){
    float w0=W1s[k*128+lane], w1=W1s[k*128+64+lane];
    float wg=W1gv[k*64+lane];
    float wq=(lane<32)?W1gq[k*32+lane]:0.0f;
#pragma unroll
    for(int t=0;t<4;t++){
      float y=AG[t*480+k];
      sm0[t]=fmaf(y,w0,sm0[t]); sm1[t]=fmaf(y,w1,sm1[t]);
      gvv[t]=fmaf(y,wg,gvv[t]); gqq[t]=fmaf(y,wq,gqq[t]);
    }
  }
#pragma unroll
  for(int t=0;t<4;t++){
    sm0[t]=siluf(sm0[t]); sm1[t]=siluf(sm1[t]);
    gvv[t]=sigmf(gvv[t]); gqq[t]=sigmf(gqq[t]);
  }
  float vm[4][3];
#pragma unroll
  for(int t=0;t<4;t++){vm[t][0]=0;vm[t][1]=0;vm[t][2]=0;}
#pragma unroll 4
  for(int j=0;j<64;j++){
    float w=W1v[j*64+lane];
#pragma unroll
    for(int t=0;t<4;t++){
#pragma unroll
      for(int c=0;c<3;c++) vm[t][c]=fmaf(AG[t*480+128+j*3+c],w,vm[t][c]);
    }
  }
#pragma unroll
  for(int t=0;t<4;t++){
#pragma unroll
    for(int c=0;c<3;c++) vm[t][c]*=gvv[t];
  }
  float qm[4][5];
#pragma unroll
  for(int t=0;t<4;t++){
#pragma unroll
    for(int c=0;c<5;c++) qm[t][c]=0;
  }
#pragma unroll 4
  for(int j=0;j<32;j++){
    float w=(lane<32)?W1q[j*32+lane]:0.0f;
#pragma unroll
    for(int t=0;t<4;t++){
#pragma unroll
      for(int c=0;c<5;c++) qm[t][c]=fmaf(AG[t*480+320+j*5+c],w,qm[t][c]);
    }
  }
#pragma unroll
  for(int t=0;t<4;t++){
#pragma unroll
    for(int c=0;c<5;c++) qm[t][c]*=gqq[t];
  }
  __syncthreads();
#pragma unroll
  for(int t=0;t<4;t++){
    AG[t*480+lane]=sm0[t]; AG[t*480+64+lane]=sm1[t];
#pragma unroll
    for(int c=0;c<3;c++) AG[t*480+128+lane*3+c]=vm[t][c];
    if(lane<32){
#pragma unroll
      for(int c=0;c<5;c++) AG[t*480+320+lane*5+c]=qm[t][c];
    }
  }
  __syncthreads();
  float fs0[4],fs1[4];
#pragma unroll
  for(int t=0;t<4;t++){ fs0[t]=S[(size_t)(nb+t)*128+lane]; fs1[t]=S[(size_t)(nb+t)*128+64+lane]; }
#pragma unroll 4
  for(int k=0;k<128;k++){
    float w0=W2s[k*128+lane], w1=W2s[k*128+64+lane];
#pragma unroll
    for(int t=0;t<4;t++){ float a=AG[t*480+k]; fs0[t]=fmaf(a,w0,fs0[t]); fs1[t]=fmaf(a,w1,fs1[t]); }
  }
#pragma unroll
  for(int t=0;t<4;t++){
    S[(size_t)(nb+t)*128+lane]=fs0[t];
    S[(size_t)(nb+t)*128+64+lane]=fs1[t];
  }
  float fv2[4][3];
#pragma unroll
  for(int t=0;t<4;t++){
#pragma unroll
    for(int c=0;c<3;c++) fv2[t][c]=V[(size_t)(nb+t)*192+lane*3+c];
  }
#pragma unroll 4
  for(int j=0;j<64;j++){
    float w=W2v[j*64+lane];
#pragma unroll
    for(int t=0;t<4;t++){
#pragma unroll
      for(int c=0;c<3;c++) fv2[t][c]=fmaf(AG[t*480+128+j*3+c],w,fv2[t][c]);
    }
  }
#pragma unroll
  for(int t=0;t<4;t++){
#pragma unroll
    for(int c=0;c<3;c++) V[(size_t)(nb+t)*192+lane*3+c]=fv2[t][c];
  }
  float fq2[4][5];
#pragma unroll
  for(int t=0;t<4;t++){
#pragma unroll
    for(int c=0;c<5;c++) fq2[t][c]=(lane<32)?Q[(size_t)(nb+t)*160+lane*5+c]:0.0f;
  }
#pragma unroll 4
  for(int j=0;j<32;j++){
    float w=(lane<32)?W2q[j*32+lane]:0.0f;
#pragma unroll
    for(int t=0;t<4;t++){
#pragma unroll
      for(int c=0;c<5;c++) fq2[t][c]=fmaf(AG[t*480+320+j*5+c],w,fq2[t][c]);
    }
  }
  if(lane<32){
#pragma unroll
    for(int t=0;t<4;t++){
#pragma unroll
      for(int c=0;c<5;c++) Q[(size_t)(nb+t)*160+lane*5+c]=fq2[t][c];
    }
  }
}

// ---------------- output head (4 waves x 4 nodes) ----------------
__global__ __launch_bounds__(256) void k_head2(const float* __restrict__ S, const float* __restrict__ tt,
    const float* __restrict__ Wf, const float* __restrict__ lng, const float* __restrict__ lnb,
    const float* __restrict__ Wh1, const float* __restrict__ Wh2, float* __restrict__ out){
  int tid=threadIdx.x; int lane=tid&63; int wv=tid>>6;
  int nb=blockIdx.x*16+wv*4;
  __shared__ float SLall[4][4*128];
  __shared__ float FLall[4][4*512];
  float* SL=SLall[wv];
  float* FL=FLall[wv];
#pragma unroll
  for(int t=0;t<4;t++){
    SL[t*128+lane]=S[(size_t)(nb+t)*128+lane];
    SL[t*128+64+lane]=S[(size_t)(nb+t)*128+64+lane];
  }
  __syncthreads();
  float fa[4][8];
#pragma unroll
  for(int t=0;t<4;t++){
#pragma unroll
    for(int i=0;i<8;i++) fa[t][i]=0;
  }
#pragma unroll 2
  for(int k=0;k<128;k++){
    float w[8];
#pragma unroll
    for(int i=0;i<8;i++) w[i]=Wf[k*512+lane+64*i];
#pragma unroll
    for(int t=0;t<4;t++){
      float sv=SL[t*128+k];
#pragma unroll
      for(int i=0;i<8;i++) fa[t][i]=fmaf(sv,w[i],fa[t][i]);
    }
  }
#pragma unroll
  for(int t=0;t<4;t++){
    float part=0;
#pragma unroll
    for(int i=0;i<8;i++) part+=fa[t][i];
    float mu=wsum64(part)*(1.0f/512.0f);
    float var=0;
#pragma unroll
    for(int i=0;i<8;i++){ float c=fa[t][i]-mu; var+=c*c; }
    var=wsum64(var)*(1.0f/512.0f);
    float rs=rsqrtf(var+1e-5f);
#pragma unroll
    for(int i=0;i<8;i++){
      int col=lane+64*i;
      FL[t*512+col]=(fa[t][i]-mu)*rs*lng[col]+lnb[col];
    }
  }
  __syncthreads();
  float ha[4][8];
#pragma unroll
  for(int t=0;t<4;t++){
#pragma unroll
    for(int i=0;i<8;i++) ha[t][i]=0;
  }
#pragma unroll 2
  for(int k=0;k<512;k++){
    float w[8];
#pragma unroll
    for(int i=0;i<8;i++) w[i]=Wh1[k*512+lane+64*i];
#pragma unroll
    for(int t=0;t<4;t++){
      float f=FL[t*512+k];
#pragma unroll
      for(int i=0;i<8;i++) ha[t][i]=fmaf(f,w[i],ha[t][i]);
    }
  }
#pragma unroll
  for(int t=0;t<4;t++){
    float p0=0,p1=0,p2=0;
#pragma unroll
    for(int i=0;i<8;i++){
      float hc=siluf(ha[t][i]);
      int col=lane+64*i;
      p0=fmaf(hc,Wh2[col*3+0],p0);
      p1=fmaf(hc,Wh2[col*3+1],p1);
      p2=fmaf(hc,Wh2[col*3+2],p2);
    }
    p0=wsum64(p0); p1=wsum64(p1); p2=wsum64(p2);
    if(lane==0){
      int n=nb+t;
      float tv=tt[n];
      float lmc=-0.25f*tv*tv*19.9f-0.05f*tv;
      float sd=sqrtf(1.0f-__expf(2.0f*lmc));
      float sc=-1.0f/sd;
      out[n*3+0]=p0*sc; out[n*3+1]=p1*sc; out[n*3+2]=p2*sc;
    }
  }
}

extern "C" void kernel_launch(void* const* d_in, const int* in_sizes, int n_in,
                              void* d_out, int out_size, void* d_ws, size_t ws_size,
                              hipStream_t stream){
  const float* pos  =(const float*)d_in[0];
  const float* tt   =(const float*)d_in[1];
  const int*   fin  =(const int*)d_in[2];
  const int*   esrc =(const int*)d_in[4];
  const int*   edst =(const int*)d_in[5];
  const float* Wemb =(const float*)d_in[6];
  const float* Wr1  =(const float*)d_in[7];
  const float* Wr2  =(const float*)d_in[8];
  const float* Wr3  =(const float*)d_in[9];
  const float* g1s  =(const float*)d_in[10];
  const float* g1v  =(const float*)d_in[11];
  const float* g1q  =(const float*)d_in[12];
  const float* Wrad1=(const float*)d_in[13];
  const float* Wrad2=(const float*)d_in[14];
  const float* Ws   =(const float*)d_in[15];
  const float* Wsd  =(const float*)d_in[16];
  const float* Wsv  =(const float*)d_in[17];
  const float* Wsq  =(const float*)d_in[18];
  const float* Wv   =(const float*)d_in[19];
  const float* Wq   =(const float*)d_in[20];
  const float* Amat =(const float*)d_in[21];
  const float* Wos  =(const float*)d_in[22];
  const float* Wov  =(const float*)d_in[23];
  const float* Woq  =(const float*)d_in[24];
  const float* g2s  =(const float*)d_in[25];
  const float* g2v  =(const float*)d_in[26];
  const float* g2q  =(const float*)d_in[27];
  const float* W1s  =(const float*)d_in[28];
  const float* W1gv =(const float*)d_in[29];
  const float* W1gq =(const float*)d_in[30];
  const float* W1v  =(const float*)d_in[31];
  const float* W1q  =(const float*)d_in[32];
  const float* W2s  =(const float*)d_in[33];
  const float* W2v  =(const float*)d_in[34];
  const float* W2q  =(const float*)d_in[35];
  const float* Wf   =(const float*)d_in[36];
  const float* lng  =(const float*)d_in[37];
  const float* lnb  =(const float*)d_in[38];
  const float* Wh1  =(const float*)d_in[39];
  const float* Wh2  =(const float*)d_in[40];

  const int N=NNODE;
  const int E=in_sizes[4];
  const int Ec=E/2;

  char* p=(char*)d_ws;
  auto alloc=[&](size_t bytes)->void*{ void* r=(void*)p; p+=(bytes+255)&~(size_t)255; return r; };
  int*   row_start=(int*)alloc((size_t)(N+1)*4);
  int*   cnt      =(int*)alloc(4);
  int*   prank    =(int*)alloc((size_t)E*4);
  float* dist     =(float*)alloc((size_t)E*4);
  float* sh       =(float*)alloc((size_t)E*8*4);
  float* cdist    =(float*)alloc((size_t)Ec*4);
  float* rbf      =(float*)alloc((size_t)Ec*128*4);
  float* dwwr     =(float*)alloc((size_t)Ec*320*4);
  float* S        =(float*)alloc((size_t)N*128*4);
  float* V        =(float*)alloc((size_t)N*192*4);
  float* Q        =(float*)alloc((size_t)N*160*4);
  float* Pa       =(float*)alloc((size_t)N*128*4);
  float* Pb       =(float*)alloc((size_t)N*128*4);
  float* Pc       =(float*)alloc((size_t)N*64*4);
  float* Pd       =(float*)alloc((size_t)N*32*4);
  float* PVb      =(float*)alloc((size_t)N*192*4);
  float* PQb      =(float*)alloc((size_t)N*160*4);
  float* aSb      =(float*)alloc((size_t)N*128*4);
  float* aVb      =(float*)alloc((size_t)N*192*4);
  float* aQb      =(float*)alloc((size_t)N*160*4);
  float* Yb       =(float*)alloc((size_t)N*480*4);

  k_csr<<<(N+1+255)/256,256,0,stream>>>(esrc,E,N,row_start);
  k_geom<<<(E+255)/256,256,0,stream>>>(pos,esrc,edst,E,dist,sh);
  hipMemsetAsync(cnt,0,4,stream);
  k_rank1<<<(E+255)/256,256,0,stream>>>(esrc,edst,dist,E,Ec,cnt,prank,cdist);
  k_rank2<<<(E+255)/256,256,0,stream>>>(esrc,edst,row_start,E,prank);
  k_rbf<<<(Ec*128+255)/256,256,0,stream>>>(cdist,Ec,rbf);
  k_dw3<<<(Ec+63)/64,256,0,stream>>>(rbf,Ec,Wr1,Wr2,Wr3,dwwr);
  k_nodeinit<<<N,64,0,stream>>>(tt,fin,Wemb,row_start,prank,sh,dwwr,S,V,Q);

  for(int i=0;i<6;i++){
    k_nodemm<<<N/16,256,0,stream>>>(S,V,Q,
        g1s+(size_t)i*128, g1v+(size_t)i*64, g1q+(size_t)i*32,
        Ws+(size_t)i*16384, Wsd+(size_t)i*16384, Wsv+(size_t)i*8192,
        Wsq+(size_t)i*4096, Wv+(size_t)i*4096, Wq+(size_t)i*1024,
        Pa,Pb,Pc,Pd,PVb,PQb);
    k_wr2<<<(Ec+31)/32,256,0,stream>>>(rbf,Ec,
        Wrad1+(size_t)i*8192, Wrad2+(size_t)i*20480, dwwr);
    k_attn<<<N,64,0,stream>>>(row_start,edst,prank,sh,dwwr,
        Pa,Pb,Pc,Pd,PVb,PQb, Amat+(size_t)i*128, aSb,aVb,aQb);
    k_ffn_a<<<N/16,256,0,stream>>>(S,V,Q,aSb,aVb,aQb,
        Wos+(size_t)i*16384, Wov+(size_t)i*4096, Woq+(size_t)i*1024,
        g2s+(size_t)i*128, g2v+(size_t)i*64, g2q+(size_t)i*32, Yb);
    k_ffn_b<<<N/16,256,0,stream>>>(S,V,Q,Yb,
        W1s+(size_t)i*16384, W1gv+(size_t)i*8192, W1gq+(size_t)i*4096,
        W1v+(size_t)i*4096, W1q+(size_t)i*1024,
        W2s+(size_t)i*16384, W2v+(size_t)i*4096, W2q+(size_t)i*1024);
  }
  k_head2<<<N/16,256,0,stream>>>(S,tt,Wf,lng,lnb,Wh1,Wh2,(float*)d_out);
}

// Round 10
// 2189.497 us; speedup vs baseline: 2.8447x; 1.4884x over previous
//
#include <hip/hip_runtime.h>
#include <math.h>

#define DEV __device__ __forceinline__

constexpr int NNODE = 8192;

DEV float wsum64(float x){
#pragma unroll
  for(int m=32;m>=1;m>>=1) x += __shfl_xor(x,m,64);
  return x;
}
DEV float siluf(float x){ return x/(1.0f+__expf(-x)); }
DEV float sigmf(float x){ return 1.0f/(1.0f+__expf(-x)); }
DEV float lreluf(float x){ return x>0.0f ? x : 0.2f*x; }
DEV float pick4(float a0,float a1,float a2,float a3,int h){
  float x=(h&1)?a1:a0;
  float y=(h&1)?a3:a2;
  return (h&2)?y:x;
}

// ---------------- CSR build ----------------
__global__ void k_csr(const int* __restrict__ esrc, int E, int N, int* __restrict__ row_start){
  int n = blockIdx.x*blockDim.x + threadIdx.x;
  if(n > N) return;
  int lo=0, hi=E;
  while(lo<hi){ int mid=(lo+hi)>>1; if(esrc[mid] < n) lo=mid+1; else hi=mid; }
  row_start[n]=lo;
}

// ---------------- per directed edge: dist + spherical harmonics ----------------
__global__ void k_geom(const float* __restrict__ pos, const int* __restrict__ esrc,
                       const int* __restrict__ edst, int E,
                       float* __restrict__ dist, float* __restrict__ sh){
  int e = blockIdx.x*blockDim.x + threadIdx.x;
  if(e>=E) return;
  int a=esrc[e], b=edst[e];
  float x=pos[3*a+0]-pos[3*b+0];
  float y=pos[3*a+1]-pos[3*b+1];
  float z=pos[3*a+2]-pos[3*b+2];
  float d=sqrtf(x*x+y*y+z*z);
  dist[e]=d;
  float id=1.0f/(d+1e-9f);
  float ux=x*id, uy=y*id, uz=z*id;
  const float s3=1.7320508075688772f, c15=3.872983346207417f, c5=2.23606797749979f;
  float* o = sh + (size_t)e*8;
  o[0]=s3*uy; o[1]=s3*uz; o[2]=s3*ux;
  o[3]=c15*ux*uy; o[4]=c15*uy*uz; o[5]=0.5f*c5*(3.0f*uz*uz-1.0f);
  o[6]=c15*ux*uz; o[7]=0.5f*c15*(ux*ux-uy*uy);
}

// ---------------- canonical pair ranking ----------------
__global__ void k_rank1(const int* __restrict__ esrc, const int* __restrict__ edst,
                        const float* __restrict__ dist, int E, int Ec,
                        int* __restrict__ cnt, int* __restrict__ prank, float* __restrict__ cdist){
  int e = blockIdx.x*blockDim.x + threadIdx.x;
  if(e>=E) return;
  int sn=esrc[e], dn=edst[e];
  if(sn<dn){
    int r=atomicAdd(cnt,1);
    if(r<Ec){ prank[e]=r; cdist[r]=dist[e]; } else prank[e]=0;
  }
}
__global__ void k_rank2(const int* __restrict__ esrc, const int* __restrict__ edst,
                        const int* __restrict__ row_start, int E, int* __restrict__ prank){
  int e = blockIdx.x*blockDim.x + threadIdx.x;
  if(e>=E) return;
  int sn=esrc[e], dn=edst[e];
  if(sn>dn){
    int lo=row_start[dn], hi=row_start[dn+1];
    while(lo<hi){ int mid=(lo+hi)>>1; if(edst[mid]<sn) lo=mid+1; else hi=mid; }
    prank[e]=prank[lo];
  }
}

// ---------------- rbf precompute ----------------
__global__ void k_rbf(const float* __restrict__ cdist, int Ec, float* __restrict__ rbf){
  int idx = blockIdx.x*blockDim.x + threadIdx.x;
  if(idx >= Ec*128) return;
  int e=idx>>7, k=idx&127;
  float d=cdist[e];
  float ck=(30.0f/127.0f)*(float)k;
  float dt=d-ck;
  const float gamma = 0.5f/((30.0f/128.0f)*(30.0f/128.0f));
  rbf[idx]=__expf(-gamma*dt*dt);
}

// ---------------- radial MLP per layer (32 edges/block) ----------------
__global__ __launch_bounds__(256) void k_wr2(const float* __restrict__ rbf, int Ec,
    const float* __restrict__ W1, const float* __restrict__ W2, float* __restrict__ wr){
  __shared__ float RB[32][132];
  __shared__ float H[32][72];
  int tid=threadIdx.x;
  int base=blockIdx.x*32;
#pragma unroll
  for(int i=0;i<16;i++){
    int idx=tid+256*i;
    int r=idx>>7, c=idx&127;
    RB[r][c]=(base+r<Ec)? rbf[(size_t)(base+r)*128+c] : 0.0f;
  }
  __syncthreads();
  int j=tid&63, g=tid>>6;
  int eg=g*8;
  float acc[8];
#pragma unroll
  for(int e=0;e<8;e++) acc[e]=0.0f;
#pragma unroll 2
  for(int k=0;k<128;k+=4){
    float w0=W1[k*64+j], w1=W1[(k+1)*64+j], w2=W1[(k+2)*64+j], w3=W1[(k+3)*64+j];
#pragma unroll
    for(int e=0;e<8;e++){
      const float4 rv=*reinterpret_cast<const float4*>(&RB[eg+e][k]);
      acc[e]=fmaf(rv.x,w0,acc[e]); acc[e]=fmaf(rv.y,w1,acc[e]);
      acc[e]=fmaf(rv.z,w2,acc[e]); acc[e]=fmaf(rv.w,w3,acc[e]);
    }
  }
#pragma unroll
  for(int e=0;e<8;e++) H[eg+e][j]=siluf(acc[e]);
  __syncthreads();
#pragma unroll 1
  for(int c0=0;c0<320;c0+=64){
    float a2[8];
#pragma unroll
    for(int e=0;e<8;e++) a2[e]=0.0f;
#pragma unroll 2
    for(int k=0;k<64;k+=4){
      float w0=W2[k*320+c0+j], w1=W2[(k+1)*320+c0+j], w2=W2[(k+2)*320+c0+j], w3=W2[(k+3)*320+c0+j];
#pragma unroll
      for(int e=0;e<8;e++){
        const float4 hv=*reinterpret_cast<const float4*>(&H[eg+e][k]);
        a2[e]=fmaf(hv.x,w0,a2[e]); a2[e]=fmaf(hv.y,w1,a2[e]);
        a2[e]=fmaf(hv.z,w2,a2[e]); a2[e]=fmaf(hv.w,w3,a2[e]);
      }
    }
#pragma unroll
    for(int e=0;e<8;e++){
      if(base+eg+e<Ec) wr[(size_t)(base+eg+e)*320+c0+j]=a2[e];
    }
  }
}

// ---------------- init edge MLP ----------------
__global__ __launch_bounds__(256) void k_dw3(const float* __restrict__ rbf, int Ec,
    const float* __restrict__ W1, const float* __restrict__ W2, const float* __restrict__ W3,
    float* __restrict__ dw){
  __shared__ float RB[64][132];
  __shared__ float H1[64][72];
  __shared__ float H2[64][72];
  int tid=threadIdx.x;
  int base=blockIdx.x*64;
#pragma unroll
  for(int i=0;i<32;i++){
    int idx=tid+256*i;
    int r=idx>>7, c=idx&127;
    RB[r][c]=(base+r<Ec)? rbf[(size_t)(base+r)*128+c] : 0.0f;
  }
  __syncthreads();
  int j=tid&63, g=tid>>6;
  int e0=g*16;
  float acc[16];
#pragma unroll
  for(int e=0;e<16;e++) acc[e]=0.0f;
#pragma unroll 2
  for(int k=0;k<128;k+=4){
    float w0=W1[k*64+j], w1=W1[(k+1)*64+j], w2=W1[(k+2)*64+j], w3=W1[(k+3)*64+j];
#pragma unroll
    for(int e=0;e<16;e++){
      const float4 rv=*reinterpret_cast<const float4*>(&RB[e0+e][k]);
      acc[e]=fmaf(rv.x,w0,acc[e]); acc[e]=fmaf(rv.y,w1,acc[e]);
      acc[e]=fmaf(rv.z,w2,acc[e]); acc[e]=fmaf(rv.w,w3,acc[e]);
    }
  }
#pragma unroll
  for(int e=0;e<16;e++) H1[e0+e][j]=siluf(acc[e]);
  __syncthreads();
#pragma unroll
  for(int e=0;e<16;e++) acc[e]=0.0f;
#pragma unroll 2
  for(int k=0;k<64;k+=4){
    float w0=W2[k*64+j], w1=W2[(k+1)*64+j], w2=W2[(k+2)*64+j], w3=W2[(k+3)*64+j];
#pragma unroll
    for(int e=0;e<16;e++){
      const float4 hv=*reinterpret_cast<const float4*>(&H1[e0+e][k]);
      acc[e]=fmaf(hv.x,w0,acc[e]); acc[e]=fmaf(hv.y,w1,acc[e]);
      acc[e]=fmaf(hv.z,w2,acc[e]); acc[e]=fmaf(hv.w,w3,acc[e]);
    }
  }
#pragma unroll
  for(int e=0;e<16;e++) H2[e0+e][j]=siluf(acc[e]);
  __syncthreads();
#pragma unroll 1
  for(int c0=0;c0<224;c0+=64){
    int c=c0+j;
    bool ok = c<224;
    int cc = ok? c : 0;
    float a2[16];
#pragma unroll
    for(int e=0;e<16;e++) a2[e]=0.0f;
#pragma unroll 2
    for(int k=0;k<64;k+=4){
      float w0=W3[k*224+cc], w1=W3[(k+1)*224+cc], w2=W3[(k+2)*224+cc], w3=W3[(k+3)*224+cc];
#pragma unroll
      for(int e=0;e<16;e++){
        const float4 hv=*reinterpret_cast<const float4*>(&H2[e0+e][k]);
        a2[e]=fmaf(hv.x,w0,a2[e]); a2[e]=fmaf(hv.y,w1,a2[e]);
        a2[e]=fmaf(hv.z,w2,a2[e]); a2[e]=fmaf(hv.w,w3,a2[e]);
      }
    }
#pragma unroll
    for(int e=0;e<16;e++){
      if(ok && base+e0+e<Ec) dw[(size_t)(base+e0+e)*224+c]=a2[e];
    }
  }
}

// ---------------- node init ----------------
__global__ __launch_bounds__(64) void k_nodeinit(const float* __restrict__ tt, const int* __restrict__ fin,
    const float* __restrict__ Wemb, const int* __restrict__ row_start, const int* __restrict__ prank,
    const float* __restrict__ sh, const float* __restrict__ dw,
    float* __restrict__ S, float* __restrict__ V, float* __restrict__ Q){
  int n=blockIdx.x, lane=threadIdx.x;
  __shared__ float te[64];
  float tn=tt[n];
  if(lane<32){
    float fr=__expf(-9.210340371976184f*((float)lane/32.0f));
    float ang=tn*10000.0f*fr;
    te[lane]=sinf(ang);
    te[32+lane]=cosf(ang);
  }
  __syncthreads();
  int f=fin[n];
  float s0=Wemb[f*128+lane], s1=Wemb[f*128+64+lane];
  for(int j=0;j<64;j++){
    float tb=te[j];
    s0=fmaf(tb,Wemb[(20+j)*128+lane],s0);
    s1=fmaf(tb,Wemb[(20+j)*128+64+lane],s1);
  }
  float aS0=0,aS1=0,aV0=0,aV1=0,aV2=0,aQ0=0,aQ1=0,aQ2=0,aQ3=0,aQ4=0;
  int e0=row_start[n], e1=row_start[n+1];
  for(int e=e0;e<e1;e++){
    const float* de = dw + (size_t)prank[e]*224;
    const float* se = sh + (size_t)e*8;
    aS0+=de[lane]; aS1+=de[64+lane];
    float w1=de[128+lane];
    aV0=fmaf(w1,-se[0],aV0); aV1=fmaf(w1,-se[1],aV1); aV2=fmaf(w1,-se[2],aV2);
    if(lane<32){
      float w2=de[192+lane];
      aQ0=fmaf(w2,se[3],aQ0); aQ1=fmaf(w2,se[4],aQ1); aQ2=fmaf(w2,se[5],aQ2);
      aQ3=fmaf(w2,se[6],aQ3); aQ4=fmaf(w2,se[7],aQ4);
    }
  }
  const float inv = 1.0f/sqrtf(15.57930850982666f);
  S[(size_t)n*128+lane]=s0+inv*aS0;
  S[(size_t)n*128+64+lane]=s1+inv*aS1;
  V[(size_t)n*192+lane*3+0]=inv*aV0;
  V[(size_t)n*192+lane*3+1]=inv*aV1;
  V[(size_t)n*192+lane*3+2]=inv*aV2;
  if(lane<32){
    Q[(size_t)n*160+lane*5+0]=inv*aQ0;
    Q[(size_t)n*160+lane*5+1]=inv*aQ1;
    Q[(size_t)n*160+lane*5+2]=inv*aQ2;
    Q[(size_t)n*160+lane*5+3]=inv*aQ3;
    Q[(size_t)n*160+lane*5+4]=inv*aQ4;
  }
}

// ---------------- eq_ln(g1) + per-node projections (4 waves x 4 nodes) ----------
__global__ __launch_bounds__(256) void k_nodemm(
    const float* __restrict__ S, const float* __restrict__ V, const float* __restrict__ Q,
    const float* __restrict__ g1s, const float* __restrict__ g1v, const float* __restrict__ g1q,
    const float* __restrict__ Ws, const float* __restrict__ Wsd, const float* __restrict__ Wsv,
    const float* __restrict__ Wsq, const float* __restrict__ Wv, const float* __restrict__ Wq,
    float* __restrict__ Pa, float* __restrict__ Pb, float* __restrict__ Pc, float* __restrict__ Pd,
    float* __restrict__ PVb, float* __restrict__ PQb){
  int tid=threadIdx.x; int lane=tid&63; int wv=tid>>6;
  int nb=blockIdx.x*16+wv*4;
  __shared__ float Yall[4][4*480];
  float* Y=Yall[wv];
  for(int t=0;t<4;t++){
    int n=nb+t;
    float s0=S[(size_t)n*128+lane], s1=S[(size_t)n*128+64+lane];
    float mu=wsum64(s0+s1)*(1.0f/128.0f);
    float c0=s0-mu, c1=s1-mu;
    float var=wsum64(c0*c0+c1*c1)*(1.0f/128.0f);
    float rs=rsqrtf(var+1e-5f);
    Y[t*480+lane]=c0*rs*g1s[lane];
    Y[t*480+64+lane]=c1*rs*g1s[64+lane];
    float vx=V[(size_t)n*192+lane*3+0], vy=V[(size_t)n*192+lane*3+1], vz=V[(size_t)n*192+lane*3+2];
    float nv=wsum64(vx*vx+vy*vy+vz*vz)*(1.0f/64.0f);
    float rv=rsqrtf(nv+1e-5f)*g1v[lane];
    Y[t*480+128+lane*3+0]=vx*rv;
    Y[t*480+128+lane*3+1]=vy*rv;
    Y[t*480+128+lane*3+2]=vz*rv;
    float q0=0,q1=0,q2=0,q3=0,q4=0,qs=0;
    if(lane<32){
      q0=Q[(size_t)n*160+lane*5+0]; q1=Q[(size_t)n*160+lane*5+1]; q2=Q[(size_t)n*160+lane*5+2];
      q3=Q[(size_t)n*160+lane*5+3]; q4=Q[(size_t)n*160+lane*5+4];
      qs=q0*q0+q1*q1+q2*q2+q3*q3+q4*q4;
    }
    float nq=wsum64(qs)*(1.0f/32.0f);
    float rq=rsqrtf(nq+1e-5f);
    if(lane<32){
      float g=g1q[lane]*rq;
      Y[t*480+320+lane*5+0]=q0*g; Y[t*480+320+lane*5+1]=q1*g; Y[t*480+320+lane*5+2]=q2*g;
      Y[t*480+320+lane*5+3]=q3*g; Y[t*480+320+lane*5+4]=q4*g;
    }
  }
  __syncthreads();
  float pa0[4],pa1[4],pb0[4],pb1[4];
#pragma unroll
  for(int t=0;t<4;t++){pa0[t]=0;pa1[t]=0;pb0[t]=0;pb1[t]=0;}
#pragma unroll 4
  for(int k=0;k<128;k++){
    float wa0=Ws[k*128+lane], wa1=Ws[k*128+64+lane];
    float wb0=Wsd[k*128+lane], wb1=Wsd[k*128+64+lane];
#pragma unroll
    for(int t=0;t<4;t++){
      float y=Y[t*480+k];
      pa0[t]=fmaf(y,wa0,pa0[t]); pa1[t]=fmaf(y,wa1,pa1[t]);
      pb0[t]=fmaf(y,wb0,pb0[t]); pb1[t]=fmaf(y,wb1,pb1[t]);
    }
  }
#pragma unroll
  for(int t=0;t<4;t++){
    size_t n=nb+t;
    Pa[n*128+lane]=pa0[t]; Pa[n*128+64+lane]=pa1[t];
    Pb[n*128+lane]=pb0[t]; Pb[n*128+64+lane]=pb1[t];
  }
  float pc[4],pd[4];
#pragma unroll
  for(int t=0;t<4;t++){pc[t]=0;pd[t]=0;}
#pragma unroll 4
  for(int k=0;k<128;k++){
    float wc=Wsv[k*64+lane];
    float wd=(lane<32)?Wsq[k*32+lane]:0.0f;
#pragma unroll
    for(int t=0;t<4;t++){
      float y=Y[t*480+k];
      pc[t]=fmaf(y,wc,pc[t]); pd[t]=fmaf(y,wd,pd[t]);
    }
  }
#pragma unroll
  for(int t=0;t<4;t++){
    size_t n=nb+t;
    Pc[n*64+lane]=pc[t];
    if(lane<32) Pd[n*32+lane]=pd[t];
  }
  float pV[4][3];
#pragma unroll
  for(int t=0;t<4;t++){pV[t][0]=0;pV[t][1]=0;pV[t][2]=0;}
#pragma unroll 4
  for(int j=0;j<64;j++){
    float w=Wv[j*64+lane];
#pragma unroll
    for(int t=0;t<4;t++){
#pragma unroll
      for(int c=0;c<3;c++) pV[t][c]=fmaf(Y[t*480+128+j*3+c],w,pV[t][c]);
    }
  }
#pragma unroll
  for(int t=0;t<4;t++){
    size_t n=nb+t;
#pragma unroll
    for(int c=0;c<3;c++) PVb[n*192+lane*3+c]=pV[t][c];
  }
  float pQ[4][5];
#pragma unroll
  for(int t=0;t<4;t++){
#pragma unroll
    for(int c=0;c<5;c++) pQ[t][c]=0;
  }
#pragma unroll 4
  for(int j=0;j<32;j++){
    float w=(lane<32)?Wq[j*32+lane]:0.0f;
#pragma unroll
    for(int t=0;t<4;t++){
#pragma unroll
      for(int c=0;c<5;c++) pQ[t][c]=fmaf(Y[t*480+320+j*5+c],w,pQ[t][c]);
    }
  }
  if(lane<32){
#pragma unroll
    for(int t=0;t<4;t++){
      size_t n=nb+t;
#pragma unroll
      for(int c=0;c<5;c++) PQb[n*160+lane*5+c]=pQ[t][c];
    }
  }
}

// ---------------- attention: single-chain online segment-softmax ----------------
__global__ __launch_bounds__(64) void k_attn(
    const int* __restrict__ row_start, const int* __restrict__ edst, const int* __restrict__ prank,
    const float* __restrict__ sh, const float* __restrict__ wr,
    const float* __restrict__ Pa, const float* __restrict__ Pb, const float* __restrict__ Pc,
    const float* __restrict__ Pd, const float* __restrict__ PVb, const float* __restrict__ PQb,
    const float* __restrict__ Amat,
    float* __restrict__ aS, float* __restrict__ aV, float* __restrict__ aQ){
  int n=blockIdx.x, lane=threadIdx.x;
  int e0=row_start[n], e1=row_start[n+1];
  float b0=Pb[(size_t)n*128+lane], b1=Pb[(size_t)n*128+64+lane];
  int d5=lane>>5;
  float A0=Amat[d5*32+(lane&31)];
  float A1=Amat[(2+d5)*32+(lane&31)];
  int hv=lane>>4;
  int hq=(lane&31)>>3;
  float M0=-1e30f,M1=-1e30f,M2=-1e30f,M3=-1e30f;
  float D0=0,D1=0,D2=0,D3=0;
  float s0a=0,s1a=0,v0a=0,v1a=0,v2a=0,q0a=0,q1a=0,q2a=0,q3a=0,q4a=0;
  for(int e=e0;e<e1;e++){
    int m=edst[e];
    const float* wre = wr + (size_t)prank[e]*320;
    const float* se  = sh + (size_t)e*8;
    float ms0=(Pa[(size_t)m*128+lane]+b0)*wre[lane];
    float ms1=(Pa[(size_t)m*128+64+lane]+b1)*wre[64+lane];
    float l0=lreluf(ms0)*A0;
    float l1=lreluf(ms1)*A1;
#pragma unroll
    for(int mk=16;mk>=1;mk>>=1){ l0+=__shfl_xor(l0,mk,32); l1+=__shfl_xor(l1,mk,32); }
    float lg0=__shfl(l0,0,64), lg1=__shfl(l0,32,64);
    float lg2=__shfl(l1,0,64), lg3=__shfl(l1,32,64);
    float Mn,f0_,f1_,f2_,f3_,e0_,e1_,e2_,e3_;
    Mn=fmaxf(M0,lg0); f0_=__expf(M0-Mn); e0_=__expf(lg0-Mn); D0=D0*f0_+e0_; M0=Mn;
    Mn=fmaxf(M1,lg1); f1_=__expf(M1-Mn); e1_=__expf(lg1-Mn); D1=D1*f1_+e1_; M1=Mn;
    Mn=fmaxf(M2,lg2); f2_=__expf(M2-Mn); e2_=__expf(lg2-Mn); D2=D2*f2_+e2_; M2=Mn;
    Mn=fmaxf(M3,lg3); f3_=__expf(M3-Mn); e3_=__expf(lg3-Mn); D3=D3*f3_+e3_; M3=Mn;
    float fs0=d5?f1_:f0_, es0=d5?e1_:e0_;
    float fs1=d5?f3_:f2_, es1=d5?e3_:e2_;
    s0a=s0a*fs0+es0*ms0;
    s1a=s1a*fs1+es1*ms1;
    float fv=pick4(f0_,f1_,f2_,f3_,hv), ev=pick4(e0_,e1_,e2_,e3_,hv);
    float aw1a=wre[128+lane], aw1b=wre[192+lane];
    float t1=Pc[(size_t)m*64+lane]*aw1a;
    float mv0=fmaf(PVb[(size_t)m*192+lane*3+0],aw1b,-t1*se[0]);
    float mv1=fmaf(PVb[(size_t)m*192+lane*3+1],aw1b,-t1*se[1]);
    float mv2=fmaf(PVb[(size_t)m*192+lane*3+2],aw1b,-t1*se[2]);
    v0a=v0a*fv+ev*mv0; v1a=v1a*fv+ev*mv1; v2a=v2a*fv+ev*mv2;
    if(lane<32){
      float fq=pick4(f0_,f1_,f2_,f3_,hq), eq=pick4(e0_,e1_,e2_,e3_,hq);
      float aw2a=wre[256+lane], aw2b=wre[288+lane];
      float t2=Pd[(size_t)m*32+lane]*aw2a;
      float mq0=fmaf(PQb[(size_t)m*160+lane*5+0],aw2b,t2*se[3]);
      float mq1=fmaf(PQb[(size_t)m*160+lane*5+1],aw2b,t2*se[4]);
      float mq2=fmaf(PQb[(size_t)m*160+lane*5+2],aw2b,t2*se[5]);
      float mq3=fmaf(PQb[(size_t)m*160+lane*5+3],aw2b,t2*se[6]);
      float mq4=fmaf(PQb[(size_t)m*160+lane*5+4],aw2b,t2*se[7]);
      q0a=q0a*fq+eq*mq0; q1a=q1a*fq+eq*mq1; q2a=q2a*fq+eq*mq2;
      q3a=q3a*fq+eq*mq3; q4a=q4a*fq+eq*mq4;
    }
  }
  float Ds0=d5?D1:D0, Ds1=d5?D3:D2;
  aS[(size_t)n*128+lane]=s0a/(Ds0+1e-9f);
  aS[(size_t)n*128+64+lane]=s1a/(Ds1+1e-9f);
  float Dv=pick4(D0,D1,D2,D3,hv);
  float iv=1.0f/(Dv+1e-9f);
  aV[(size_t)n*192+lane*3+0]=v0a*iv;
  aV[(size_t)n*192+lane*3+1]=v1a*iv;
  aV[(size_t)n*192+lane*3+2]=v2a*iv;
  if(lane<32){
    float Dq=pick4(D0,D1,D2,D3,hq);
    float iq=1.0f/(Dq+1e-9f);
    aQ[(size_t)n*160+lane*5+0]=q0a*iq;
    aQ[(size_t)n*160+lane*5+1]=q1a*iq;
    aQ[(size_t)n*160+lane*5+2]=q2a*iq;
    aQ[(size_t)n*160+lane*5+3]=q3a*iq;
    aQ[(size_t)n*160+lane*5+4]=q4a*iq;
  }
}

// ---------------- ffn_a: attn-out proj + residual + eq_ln(g2) (4w x 4n) ---------
__global__ __launch_bounds__(256) void k_ffn_a(
    float* __restrict__ S, float* __restrict__ V, float* __restrict__ Q,
    const float* __restrict__ aS, const float* __restrict__ aV, const float* __restrict__ aQ,
    const float* __restrict__ Wos, const float* __restrict__ Wov, const float* __restrict__ Woq,
    const float* __restrict__ g2s, const float* __restrict__ g2v, const float* __restrict__ g2q,
    float* __restrict__ Yb){
  int tid=threadIdx.x; int lane=tid&63; int wv=tid>>6;
  int nb=blockIdx.x*16+wv*4;
  __shared__ float AGall[4][4*480];
  float* AG=AGall[wv];
#pragma unroll
  for(int t=0;t<4;t++){
    size_t n=nb+t;
    AG[t*480+lane]=aS[n*128+lane];
    AG[t*480+64+lane]=aS[n*128+64+lane];
#pragma unroll
    for(int c=0;c<3;c++) AG[t*480+128+lane*3+c]=aV[n*192+lane*3+c];
    if(lane<32){
#pragma unroll
      for(int c=0;c<5;c++) AG[t*480+320+lane*5+c]=aQ[n*160+lane*5+c];
    }
  }
  __syncthreads();
  float su0[4],su1[4];
#pragma unroll
  for(int t=0;t<4;t++){ su0[t]=S[(size_t)(nb+t)*128+lane]; su1[t]=S[(size_t)(nb+t)*128+64+lane]; }
#pragma unroll 4
  for(int k=0;k<128;k++){
    float w0=Wos[k*128+lane], w1=Wos[k*128+64+lane];
#pragma unroll
    for(int t=0;t<4;t++){ float a=AG[t*480+k]; su0[t]=fmaf(a,w0,su0[t]); su1[t]=fmaf(a,w1,su1[t]); }
  }
  float vu[4][3];
#pragma unroll
  for(int t=0;t<4;t++){
#pragma unroll
    for(int c=0;c<3;c++) vu[t][c]=V[(size_t)(nb+t)*192+lane*3+c];
  }
#pragma unroll 4
  for(int j=0;j<64;j++){
    float w=Wov[j*64+lane];
#pragma unroll
    for(int t=0;t<4;t++){
#pragma unroll
      for(int c=0;c<3;c++) vu[t][c]=fmaf(AG[t*480+128+j*3+c],w,vu[t][c]);
    }
  }
  float qu[4][5];
#pragma unroll
  for(int t=0;t<4;t++){
#pragma unroll
    for(int c=0;c<5;c++) qu[t][c]=(lane<32)?Q[(size_t)(nb+t)*160+lane*5+c]:0.0f;
  }
#pragma unroll 4
  for(int j=0;j<32;j++){
    float w=(lane<32)?Woq[j*32+lane]:0.0f;
#pragma unroll
    for(int t=0;t<4;t++){
#pragma unroll
      for(int c=0;c<5;c++) qu[t][c]=fmaf(AG[t*480+320+j*5+c],w,qu[t][c]);
    }
  }
  for(int t=0;t<4;t++){
    size_t n=nb+t;
    S[n*128+lane]=su0[t];
    S[n*128+64+lane]=su1[t];
    float mu=wsum64(su0[t]+su1[t])*(1.0f/128.0f);
    float c0=su0[t]-mu, c1=su1[t]-mu;
    float var=wsum64(c0*c0+c1*c1)*(1.0f/128.0f);
    float rs=rsqrtf(var+1e-5f);
    Yb[n*480+lane]=c0*rs*g2s[lane];
    Yb[n*480+64+lane]=c1*rs*g2s[64+lane];
    float vx=vu[t][0], vy=vu[t][1], vz=vu[t][2];
    V[n*192+lane*3+0]=vx; V[n*192+lane*3+1]=vy; V[n*192+lane*3+2]=vz;
    float nv=wsum64(vx*vx+vy*vy+vz*vz)*(1.0f/64.0f);
    float rv=rsqrtf(nv+1e-5f)*g2v[lane];
    Yb[n*480+128+lane*3+0]=vx*rv;
    Yb[n*480+128+lane*3+1]=vy*rv;
    Yb[n*480+128+lane*3+2]=vz*rv;
    float qs=0;
    if(lane<32){
#pragma unroll
      for(int c=0;c<5;c++){ Q[n*160+lane*5+c]=qu[t][c]; qs+=qu[t][c]*qu[t][c]; }
    }
    float nq=wsum64(qs)*(1.0f/32.0f);
    float rq=rsqrtf(nq+1e-5f);
    if(lane<32){
      float g=g2q[lane]*rq;
#pragma unroll
      for(int c=0;c<5;c++) Yb[n*480+320+lane*5+c]=qu[t][c]*g;
    }
  }
}

// ---------------- ffn_b: gated FFN + residual (4w x 4n) -------------------------
__global__ __launch_bounds__(256) void k_ffn_b(
    float* __restrict__ S, float* __restrict__ V, float* __restrict__ Q,
    const float* __restrict__ Yb,
    const float* __restrict__ W1s, const float* __restrict__ W1gv, const float* __restrict__ W1gq,
    const float* __restrict__ W1v, const float* __restrict__ W1q,
    const float* __restrict__ W2s, const float* __restrict__ W2v, const float* __restrict__ W2q){
  int tid=threadIdx.x; int lane=tid&63; int wv=tid>>6;
  int nb=blockIdx.x*16+wv*4;
  __shared__ float AGall[4][4*480];
  float* AG=AGall[wv];
#pragma unroll
  for(int t=0;t<4;t++){
    size_t n=nb+t;
    AG[t*480+lane]=Yb[n*480+lane];
    AG[t*480+64+lane]=Yb[n*480+64+lane];
#pragma unroll
    for(int c=0;c<3;c++) AG[t*480+128+lane*3+c]=Yb[n*480+128+lane*3+c];
    if(lane<32){
#pragma unroll
      for(int c=0;c<5;c++) AG[t*480+320+lane*5+c]=Yb[n*480+320+lane*5+c];
    }
  }
  __syncthreads();
  float sm0[4],sm1[4],gvv[4],gqq[4];
#pragma unroll
  for(int t=0;t<4;t++){sm0[t]=0;sm1[t]=0;gvv[t]=0;gqq[t]=0;}
#pragma unroll 4
  for(int k=0;k<128;k++){
    float w0=W1s[k*128+lane], w1=W1s[k*128+64+lane];
    float wg=W1gv[k*64+lane];
    float wq=(lane<32)?W1gq[k*32+lane]:0.0f;
#pragma unroll
    for(int t=0;t<4;t++){
      float y=AG[t*480+k];
      sm0[t]=fmaf(y,w0,sm0[t]); sm1[t]=fmaf(y,w1,sm1[t]);
      gvv[t]=fmaf(y,wg,gvv[t]); gqq[t]=fmaf(y,wq,gqq[t]);
    }
  }
#pragma unroll
  for(int t=0;t<4;t++){
    sm0[t]=siluf(sm0[t]); sm1[t]=siluf(sm1[t]);
    gvv[t]=sigmf(gvv[t]); gqq[t]=sigmf(gqq[t]);
  }
  float vm[4][3];
#pragma unroll
  for(int t=0;t<4;t++){vm[t][0]=0;vm[t][1]=0;vm[t][2]=0;}
#pragma unroll 4
  for(int j=0;j<64;j++){
    float w=W1v[j*64+lane];
#pragma unroll
    for(int t=0;t<4;t++){
#pragma unroll
      for(int c=0;c<3;c++) vm[t][c]=fmaf(AG[t*480+128+j*3+c],w,vm[t][c]);
    }
  }
#pragma unroll
  for(int t=0;t<4;t++){
#pragma unroll
    for(int c=0;c<3;c++) vm[t][c]*=gvv[t];
  }
  float qm[4][5];
#pragma unroll
  for(int t=0;t<4;t++){
#pragma unroll
    for(int c=0;c<5;c++) qm[t][c]=0;
  }
#pragma unroll 4
  for(int j=0;j<32;j++){
    float w=(lane<32)?W1q[j*32+lane]:0.0f;
#pragma unroll
    for(int t=0;t<4;t++){
#pragma unroll
      for(int c=0;c<5;c++) qm[t][c]=fmaf(AG[t*480+320+j*5+c],w,qm[t][c]);
    }
  }
#pragma unroll
  for(int t=0;t<4;t++){
#pragma unroll
    for(int c=0;c<5;c++) qm[t][c]*=gqq[t];
  }
  __syncthreads();
#pragma unroll
  for(int t=0;t<4;t++){
    AG[t*480+lane]=sm0[t]; AG[t*480+64+lane]=sm1[t];
#pragma unroll
    for(int c=0;c<3;c++) AG[t*480+128+lane*3+c]=vm[t][c];
    if(lane<32){
#pragma unroll
      for(int c=0;c<5;c++) AG[t*480+320+lane*5+c]=qm[t][c];
    }
  }
  __syncthreads();
  float fs0[4],fs1[4];
#pragma unroll
  for(int t=0;t<4;t++){ fs0[t]=S[(size_t)(nb+t)*128+lane]; fs1[t]=S[(size_t)(nb+t)*128+64+lane]; }
#pragma unroll 4
  for(int k=0;k<128;k++){
    float w0=W2s[k*128+lane], w1=W2s[k*128+64+lane];
#pragma unroll
    for(int t=0;t<4;t++){ float a=AG[t*480+k]; fs0[t]=fmaf(a,w0,fs0[t]); fs1[t]=fmaf(a,w1,fs1[t]); }
  }
#pragma unroll
  for(int t=0;t<4;t++){
    S[(size_t)(nb+t)*128+lane]=fs0[t];
    S[(size_t)(nb+t)*128+64+lane]=fs1[t];
  }
  float fv2[4][3];
#pragma unroll
  for(int t=0;t<4;t++){
#pragma unroll
    for(int c=0;c<3;c++) fv2[t][c]=V[(size_t)(nb+t)*192+lane*3+c];
  }
#pragma unroll 4
  for(int j=0;j<64;j++){
    float w=W2v[j*64+lane];
#pragma unroll
    for(int t=0;t<4;t++){
#pragma unroll
      for(int c=0;c<3;c++) fv2[t][c]=fmaf(AG[t*480+128+j*3+c],w,fv2[t][c]);
    }
  }
#pragma unroll
  for(int t=0;t<4;t++){
#pragma unroll
    for(int c=0;c<3;c++) V[(size_t)(nb+t)*192+lane*3+c]=fv2[t][c];
  }
  float fq2[4][5];
#pragma unroll
  for(int t=0;t<4;t++){
#pragma unroll
    for(int c=0;c<5;c++) fq2[t][c]=(lane<32)?Q[(size_t)(nb+t)*160+lane*5+c]:0.0f;
  }
#pragma unroll 4
  for(int j=0;j<32;j++){
    float w=(lane<32)?W2q[j*32+lane]:0.0f;
#pragma unroll
    for(int t=0;t<4;t++){
#pragma unroll
      for(int c=0;c<5;c++) fq2[t][c]=fmaf(AG[t*480+320+j*5+c],w,fq2[t][c]);
    }
  }
  if(lane<32){
#pragma unroll
    for(int t=0;t<4;t++){
#pragma unroll
      for(int c=0;c<5;c++) Q[(size_t)(nb+t)*160+lane*5+c]=fq2[t][c];
    }
  }
}

// ---------------- output head (4 waves x 4 nodes) ----------------
__global__ __launch_bounds__(256) void k_head2(const float* __restrict__ S, const float* __restrict__ tt,
    const float* __restrict__ Wf, const float* __restrict__ lng, const float* __restrict__ lnb,
    const float* __restrict__ Wh1, const float* __restrict__ Wh2, float* __restrict__ out){
  int tid=threadIdx.x; int lane=tid&63; int wv=tid>>6;
  int nb=blockIdx.x*16+wv*4;
  __shared__ float SLall[4][4*128];
  __shared__ float FLall[4][4*512];
  float* SL=SLall[wv];
  float* FL=FLall[wv];
#pragma unroll
  for(int t=0;t<4;t++){
    SL[t*128+lane]=S[(size_t)(nb+t)*128+lane];
    SL[t*128+64+lane]=S[(size_t)(nb+t)*128+64+lane];
  }
  __syncthreads();
  float fa[4][8];
#pragma unroll
  for(int t=0;t<4;t++){
#pragma unroll
    for(int i=0;i<8;i++) fa[t][i]=0;
  }
#pragma unroll 2
  for(int k=0;k<128;k++){
    float w[8];
#pragma unroll
    for(int i=0;i<8;i++) w[i]=Wf[k*512+lane+64*i];
#pragma unroll
    for(int t=0;t<4;t++){
      float sv=SL[t*128+k];
#pragma unroll
      for(int i=0;i<8;i++) fa[t][i]=fmaf(sv,w[i],fa[t][i]);
    }
  }
#pragma unroll
  for(int t=0;t<4;t++){
    float part=0;
#pragma unroll
    for(int i=0;i<8;i++) part+=fa[t][i];
    float mu=wsum64(part)*(1.0f/512.0f);
    float var=0;
#pragma unroll
    for(int i=0;i<8;i++){ float c=fa[t][i]-mu; var+=c*c; }
    var=wsum64(var)*(1.0f/512.0f);
    float rs=rsqrtf(var+1e-5f);
#pragma unroll
    for(int i=0;i<8;i++){
      int col=lane+64*i;
      FL[t*512+col]=(fa[t][i]-mu)*rs*lng[col]+lnb[col];
    }
  }
  __syncthreads();
  float ha[4][8];
#pragma unroll
  for(int t=0;t<4;t++){
#pragma unroll
    for(int i=0;i<8;i++) ha[t][i]=0;
  }
#pragma unroll 2
  for(int k=0;k<512;k++){
    float w[8];
#pragma unroll
    for(int i=0;i<8;i++) w[i]=Wh1[k*512+lane+64*i];
#pragma unroll
    for(int t=0;t<4;t++){
      float f=FL[t*512+k];
#pragma unroll
      for(int i=0;i<8;i++) ha[t][i]=fmaf(f,w[i],ha[t][i]);
    }
  }
#pragma unroll
  for(int t=0;t<4;t++){
    float p0=0,p1=0,p2=0;
#pragma unroll
    for(int i=0;i<8;i++){
      float hc=siluf(ha[t][i]);
      int col=lane+64*i;
      p0=fmaf(hc,Wh2[col*3+0],p0);
      p1=fmaf(hc,Wh2[col*3+1],p1);
      p2=fmaf(hc,Wh2[col*3+2],p2);
    }
    p0=wsum64(p0); p1=wsum64(p1); p2=wsum64(p2);
    if(lane==0){
      int n=nb+t;
      float tv=tt[n];
      float lmc=-0.25f*tv*tv*19.9f-0.05f*tv;
      float sd=sqrtf(1.0f-__expf(2.0f*lmc));
      float sc=-1.0f/sd;
      out[n*3+0]=p0*sc; out[n*3+1]=p1*sc; out[n*3+2]=p2*sc;
    }
  }
}

extern "C" void kernel_launch(void* const* d_in, const int* in_sizes, int n_in,
                              void* d_out, int out_size, void* d_ws, size_t ws_size,
                              hipStream_t stream){
  const float* pos  =(const float*)d_in[0];
  const float* tt   =(const float*)d_in[1];
  const int*   fin  =(const int*)d_in[2];
  const int*   esrc =(const int*)d_in[4];
  const int*   edst =(const int*)d_in[5];
  const float* Wemb =(const float*)d_in[6];
  const float* Wr1  =(const float*)d_in[7];
  const float* Wr2  =(const float*)d_in[8];
  const float* Wr3  =(const float*)d_in[9];
  const float* g1s  =(const float*)d_in[10];
  const float* g1v  =(const float*)d_in[11];
  const float* g1q  =(const float*)d_in[12];
  const float* Wrad1=(const float*)d_in[13];
  const float* Wrad2=(const float*)d_in[14];
  const float* Ws   =(const float*)d_in[15];
  const float* Wsd  =(const float*)d_in[16];
  const float* Wsv  =(const float*)d_in[17];
  const float* Wsq  =(const float*)d_in[18];
  const float* Wv   =(const float*)d_in[19];
  const float* Wq   =(const float*)d_in[20];
  const float* Amat =(const float*)d_in[21];
  const float* Wos  =(const float*)d_in[22];
  const float* Wov  =(const float*)d_in[23];
  const float* Woq  =(const float*)d_in[24];
  const float* g2s  =(const float*)d_in[25];
  const float* g2v  =(const float*)d_in[26];
  const float* g2q  =(const float*)d_in[27];
  const float* W1s  =(const float*)d_in[28];
  const float* W1gv =(const float*)d_in[29];
  const float* W1gq =(const float*)d_in[30];
  const float* W1v  =(const float*)d_in[31];
  const float* W1q  =(const float*)d_in[32];
  const float* W2s  =(const float*)d_in[33];
  const float* W2v  =(const float*)d_in[34];
  const float* W2q  =(const float*)d_in[35];
  const float* Wf   =(const float*)d_in[36];
  const float* lng  =(const float*)d_in[37];
  const float* lnb  =(const float*)d_in[38];
  const float* Wh1  =(const float*)d_in[39];
  const float* Wh2  =(const float*)d_in[40];

  const int N=NNODE;
  const int E=in_sizes[4];
  const int Ec=E/2;

  char* p=(char*)d_ws;
  auto alloc=[&](size_t bytes)->void*{ void* r=(void*)p; p+=(bytes+255)&~(size_t)255; return r; };
  int*   row_start=(int*)alloc((size_t)(N+1)*4);
  int*   cnt      =(int*)alloc(4);
  int*   prank    =(int*)alloc((size_t)E*4);
  float* dist     =(float*)alloc((size_t)E*4);
  float* sh       =(float*)alloc((size_t)E*8*4);
  float* cdist    =(float*)alloc((size_t)Ec*4);
  float* rbf      =(float*)alloc((size_t)Ec*128*4);
  float* dwwr     =(float*)alloc((size_t)Ec*320*4);
  float* S        =(float*)alloc((size_t)N*128*4);
  float* V        =(float*)alloc((size_t)N*192*4);
  float* Q        =(float*)alloc((size_t)N*160*4);
  float* Pa       =(float*)alloc((size_t)N*128*4);
  float* Pb       =(float*)alloc((size_t)N*128*4);
  float* Pc       =(float*)alloc((size_t)N*64*4);
  float* Pd       =(float*)alloc((size_t)N*32*4);
  float* PVb      =(float*)alloc((size_t)N*192*4);
  float* PQb      =(float*)alloc((size_t)N*160*4);
  float* aSb      =(float*)alloc((size_t)N*128*4);
  float* aVb      =(float*)alloc((size_t)N*192*4);
  float* aQb      =(float*)alloc((size_t)N*160*4);
  float* Yb       =(float*)alloc((size_t)N*480*4);

  k_csr<<<(N+1+255)/256,256,0,stream>>>(esrc,E,N,row_start);
  k_geom<<<(E+255)/256,256,0,stream>>>(pos,esrc,edst,E,dist,sh);
  hipMemsetAsync(cnt,0,4,stream);
  k_rank1<<<(E+255)/256,256,0,stream>>>(esrc,edst,dist,E,Ec,cnt,prank,cdist);
  k_rank2<<<(E+255)/256,256,0,stream>>>(esrc,edst,row_start,E,prank);
  k_rbf<<<(Ec*128+255)/256,256,0,stream>>>(cdist,Ec,rbf);
  k_dw3<<<(Ec+63)/64,256,0,stream>>>(rbf,Ec,Wr1,Wr2,Wr3,dwwr);
  k_nodeinit<<<N,64,0,stream>>>(tt,fin,Wemb,row_start,prank,sh,dwwr,S,V,Q);

  for(int i=0;i<6;i++){
    k_nodemm<<<N/16,256,0,stream>>>(S,V,Q,
        g1s+(size_t)i*128, g1v+(size_t)i*64, g1q+(size_t)i*32,
        Ws+(size_t)i*16384, Wsd+(size_t)i*16384, Wsv+(size_t)i*8192,
        Wsq+(size_t)i*4096, Wv+(size_t)i*4096, Wq+(size_t)i*1024,
        Pa,Pb,Pc,Pd,PVb,PQb);
    k_wr2<<<(Ec+31)/32,256,0,stream>>>(rbf,Ec,
        Wrad1+(size_t)i*8192, Wrad2+(size_t)i*20480, dwwr);
    k_attn<<<N,64,0,stream>>>(row_start,edst,prank,sh,dwwr,
        Pa,Pb,Pc,Pd,PVb,PQb, Amat+(size_t)i*128, aSb,aVb,aQb);
    k_ffn_a<<<N/16,256,0,stream>>>(S,V,Q,aSb,aVb,aQb,
        Wos+(size_t)i*16384, Wov+(size_t)i*4096, Woq+(size_t)i*1024,
        g2s+(size_t)i*128, g2v+(size_t)i*64, g2q+(size_t)i*32, Yb);
    k_ffn_b<<<N/16,256,0,stream>>>(S,V,Q,Yb,
        W1s+(size_t)i*16384, W1gv+(size_t)i*8192, W1gq+(size_t)i*4096,
        W1v+(size_t)i*4096, W1q+(size_t)i*1024,
        W2s+(size_t)i*16384, W2v+(size_t)i*4096, W2q+(size_t)i*1024);
  }
  k_head2<<<N/16,256,0,stream>>>(S,tt,Wf,lng,lnb,Wh1,Wh2,(float*)d_out);
}